// Round 2
// baseline (17941.064 us; speedup 1.0000x reference)
//
#include <hip/hip_runtime.h>

// ---------------------------------------------------------------------------
// VQ-VAE forward, fp32 direct implementation, batch-chunked to fit ws_size.
// Per-chunk pipeline: encoder -> VQ -> decoder, arena peak 80 MiB/batch-elem.
// ---------------------------------------------------------------------------

// ============================ conv3x3 stride 1 =============================
// Output tile 32x32, 256 threads, each thread: 4 horizontal pixels x 16 outch.
template<bool RELU, bool ADD>
__global__ __launch_bounds__(256) void conv3x3_s1(
    const float* __restrict__ in, const float* __restrict__ wt,
    const float* __restrict__ bias, const float* __restrict__ res,
    float* __restrict__ out, int Cin, int Cout, int H, int W)
{
    const int coChunks = (Cout + 15) >> 4;
    const int b   = blockIdx.z / coChunks;
    const int co0 = (blockIdx.z % coChunks) << 4;
    const int x0  = blockIdx.x * 32;
    const int y0  = blockIdx.y * 32;
    const int tid = threadIdx.x;
    const int tx  = (tid & 7) << 2;   // 0..28 step 4
    const int ty  = tid >> 3;         // 0..31

    __shared__ float sIn[8][34][36];
    __shared__ float sW[8][16][12];

    float acc[4][16];
#pragma unroll
    for (int p = 0; p < 4; ++p)
#pragma unroll
        for (int c = 0; c < 16; ++c) acc[p][c] = 0.f;

    const float* inB = in + (size_t)b * Cin * H * W;

    for (int ci0 = 0; ci0 < Cin; ci0 += 8) {
        for (int idx = tid; idx < 8 * 34 * 34; idx += 256) {
            int ci  = idx / 1156;
            int rem = idx - ci * 1156;
            int yy  = rem / 34;
            int xx  = rem - yy * 34;
            int gci = ci0 + ci;
            int gy  = y0 + yy - 1;
            int gx  = x0 + xx - 1;
            float v = 0.f;
            if (gci < Cin && (unsigned)gy < (unsigned)H && (unsigned)gx < (unsigned)W)
                v = inB[((size_t)gci * H + gy) * W + gx];
            sIn[ci][yy][xx] = v;
        }
        for (int idx = tid; idx < 8 * 16 * 9; idx += 256) {
            int ci  = idx / 144;
            int rem = idx - ci * 144;
            int co  = rem / 9;
            int k   = rem - co * 9;
            float v = 0.f;
            if (ci0 + ci < Cin && co0 + co < Cout)
                v = wt[(((size_t)(co0 + co)) * Cin + (ci0 + ci)) * 9 + k];
            sW[ci][co][k] = v;
        }
        __syncthreads();

#pragma unroll 1
        for (int ci = 0; ci < 8; ++ci) {
            float iv[3][6];
#pragma unroll
            for (int dy = 0; dy < 3; ++dy)
#pragma unroll
                for (int xx = 0; xx < 6; ++xx)
                    iv[dy][xx] = sIn[ci][ty + dy][tx + xx];
#pragma unroll
            for (int co = 0; co < 16; ++co) {
                float w9[9];
#pragma unroll
                for (int k = 0; k < 9; ++k) w9[k] = sW[ci][co][k];
#pragma unroll
                for (int p = 0; p < 4; ++p) {
                    float s = acc[p][co];
                    s = fmaf(iv[0][p + 0], w9[0], s);
                    s = fmaf(iv[0][p + 1], w9[1], s);
                    s = fmaf(iv[0][p + 2], w9[2], s);
                    s = fmaf(iv[1][p + 0], w9[3], s);
                    s = fmaf(iv[1][p + 1], w9[4], s);
                    s = fmaf(iv[1][p + 2], w9[5], s);
                    s = fmaf(iv[2][p + 0], w9[6], s);
                    s = fmaf(iv[2][p + 1], w9[7], s);
                    s = fmaf(iv[2][p + 2], w9[8], s);
                    acc[p][co] = s;
                }
            }
        }
        __syncthreads();
    }

    const int oy = y0 + ty;
    const int ox = x0 + tx;
#pragma unroll 1
    for (int co = 0; co < 16; ++co) {
        int gco = co0 + co;
        if (gco >= Cout) break;
        float bv = bias[gco];
        size_t oidx = (((size_t)b * Cout + gco) * H + oy) * W + ox;
        float v0 = acc[0][co] + bv;
        float v1 = acc[1][co] + bv;
        float v2 = acc[2][co] + bv;
        float v3 = acc[3][co] + bv;
        if constexpr (ADD) {
            float4 rv = *reinterpret_cast<const float4*>(res + oidx);
            v0 += rv.x; v1 += rv.y; v2 += rv.z; v3 += rv.w;
        }
        if constexpr (RELU) {
            v0 = fmaxf(v0, 0.f); v1 = fmaxf(v1, 0.f);
            v2 = fmaxf(v2, 0.f); v3 = fmaxf(v3, 0.f);
        }
        float4 r; r.x = v0; r.y = v1; r.z = v2; r.w = v3;
        *reinterpret_cast<float4*>(out + oidx) = r;
    }
}

// ============================ conv3x3 stride 2 =============================
template<bool RELU>
__global__ __launch_bounds__(256) void conv3x3_s2(
    const float* __restrict__ in, const float* __restrict__ wt,
    const float* __restrict__ bias, float* __restrict__ out,
    int Cin, int Cout, int Hi, int Wi)
{
    const int Ho = Hi >> 1, Wo = Wi >> 1;
    const int coChunks = (Cout + 15) >> 4;
    const int b   = blockIdx.z / coChunks;
    const int co0 = (blockIdx.z % coChunks) << 4;
    const int x0  = blockIdx.x * 32;
    const int y0  = blockIdx.y * 16;
    const int tid = threadIdx.x;
    const int tx  = tid & 15;
    const int ty  = tid >> 4;

    __shared__ float sIn[4][34][68];
    __shared__ float sW[4][16][12];

    float acc[2][16];
#pragma unroll
    for (int p = 0; p < 2; ++p)
#pragma unroll
        for (int c = 0; c < 16; ++c) acc[p][c] = 0.f;

    const float* inB = in + (size_t)b * Cin * Hi * Wi;

    for (int ci0 = 0; ci0 < Cin; ci0 += 4) {
        for (int idx = tid; idx < 4 * 34 * 66; idx += 256) {
            int ci  = idx / 2244;
            int rem = idx - ci * 2244;
            int yy  = rem / 66;
            int xx  = rem - yy * 66;
            int gy  = 2 * y0 - 1 + yy;
            int gx  = 2 * x0 - 1 + xx;
            float v = 0.f;
            if (ci0 + ci < Cin && (unsigned)gy < (unsigned)Hi && (unsigned)gx < (unsigned)Wi)
                v = inB[((size_t)(ci0 + ci) * Hi + gy) * Wi + gx];
            sIn[ci][yy][xx] = v;
        }
        for (int idx = tid; idx < 4 * 16 * 9; idx += 256) {
            int ci  = idx / 144;
            int rem = idx - ci * 144;
            int co  = rem / 9;
            int k   = rem - co * 9;
            float v = 0.f;
            if (ci0 + ci < Cin && co0 + co < Cout)
                v = wt[(((size_t)(co0 + co)) * Cin + (ci0 + ci)) * 9 + k];
            sW[ci][co][k] = v;
        }
        __syncthreads();

#pragma unroll 1
        for (int ci = 0; ci < 4; ++ci) {
            float iv[3][5];
#pragma unroll
            for (int dy = 0; dy < 3; ++dy)
#pragma unroll
                for (int xx = 0; xx < 5; ++xx)
                    iv[dy][xx] = sIn[ci][2 * ty + dy][4 * tx + xx];
#pragma unroll
            for (int co = 0; co < 16; ++co) {
                float w9[9];
#pragma unroll
                for (int k = 0; k < 9; ++k) w9[k] = sW[ci][co][k];
#pragma unroll
                for (int p = 0; p < 2; ++p) {
                    float s = acc[p][co];
                    s = fmaf(iv[0][2 * p + 0], w9[0], s);
                    s = fmaf(iv[0][2 * p + 1], w9[1], s);
                    s = fmaf(iv[0][2 * p + 2], w9[2], s);
                    s = fmaf(iv[1][2 * p + 0], w9[3], s);
                    s = fmaf(iv[1][2 * p + 1], w9[4], s);
                    s = fmaf(iv[1][2 * p + 2], w9[5], s);
                    s = fmaf(iv[2][2 * p + 0], w9[6], s);
                    s = fmaf(iv[2][2 * p + 1], w9[7], s);
                    s = fmaf(iv[2][2 * p + 2], w9[8], s);
                    acc[p][co] = s;
                }
            }
        }
        __syncthreads();
    }

    const int oy = y0 + ty;
    const int ox = x0 + 2 * tx;
#pragma unroll 1
    for (int co = 0; co < 16; ++co) {
        int gco = co0 + co;
        if (gco >= Cout) break;
        float bv = bias[gco];
        size_t oidx = (((size_t)b * Cout + gco) * Ho + oy) * Wo + ox;
        float v0 = acc[0][co] + bv;
        float v1 = acc[1][co] + bv;
        if constexpr (RELU) { v0 = fmaxf(v0, 0.f); v1 = fmaxf(v1, 0.f); }
        float2 r; r.x = v0; r.y = v1;
        *reinterpret_cast<float2*>(out + oidx) = r;
    }
}

// =============================== conv1x1 ===================================
__global__ __launch_bounds__(256) void conv1x1(
    const float* __restrict__ in, const float* __restrict__ wt,
    const float* __restrict__ bias, float* __restrict__ out,
    int Cin, int Cout, int HW)
{
    const int b    = blockIdx.y;
    const int co0  = blockIdx.z << 5;
    const int base = blockIdx.x * 512;
    const int t    = threadIdx.x;
    const float* inB = in + (size_t)b * Cin * HW + base + t;

    float acc0[32], acc1[32];
#pragma unroll
    for (int c = 0; c < 32; ++c) { acc0[c] = 0.f; acc1[c] = 0.f; }

    for (int ci = 0; ci < Cin; ++ci) {
        float v0 = inB[(size_t)ci * HW];
        float v1 = inB[(size_t)ci * HW + 256];
#pragma unroll
        for (int co = 0; co < 32; ++co) {
            float wv = wt[(size_t)(co0 + co) * Cin + ci];
            acc0[co] = fmaf(v0, wv, acc0[co]);
            acc1[co] = fmaf(v1, wv, acc1[co]);
        }
    }
#pragma unroll 1
    for (int co = 0; co < 32; ++co) {
        int gco = co0 + co;
        float bv = bias[gco];
        size_t oidx = ((size_t)b * Cout + gco) * HW + base + t;
        out[oidx]       = acc0[co] + bv;
        out[oidx + 256] = acc1[co] + bv;
    }
}

// ========================= nearest 2x upsample =============================
__global__ void upsample2x(const float* __restrict__ in, float* __restrict__ out,
                           int BC, int Hi, int Wi)
{
    long total2 = (long)BC * (2 * Hi) * Wi;
    long idx = (long)blockIdx.x * 256 + threadIdx.x;
    if (idx >= total2) return;
    int  x2 = (int)(idx % Wi);
    long r  = idx / Wi;
    int  y  = (int)(r % (2 * Hi));
    long bc = r / (2 * Hi);
    float v = in[(bc * Hi + (y >> 1)) * Wi + x2];
    float2 o; o.x = v; o.y = v;
    reinterpret_cast<float2*>(out)[idx] = o;
}

// ========================= codebook preparation ============================
__global__ void cb_transpose(const float* __restrict__ cb, float* __restrict__ cbT)
{
    int idx = blockIdx.x * 256 + threadIdx.x;    // 1024*128
    if (idx < 1024 * 128) {
        int k = idx >> 7, e = idx & 127;
        cbT[e * 1024 + k] = cb[idx];
    }
}

__global__ void cb_c2(const float* __restrict__ cbT, float* __restrict__ c2)
{
    int k = blockIdx.x * 256 + threadIdx.x;
    if (k < 1024) {
        float s = 0.f;
        for (int e = 0; e < 128; ++e) {
            float v = cbT[e * 1024 + k];
            s = fmaf(v, v, s);
        }
        c2[k] = s;
    }
}

// ============================== quantizer ==================================
// 16 rows/block; d = (||z||^2 - 2*dot) + ||c||^2; lowest-index tie-break via
// packed (f32-bits, idx) u64 min. Writes straight-through q and sse partials.
__global__ __launch_bounds__(256) void vq_argmin(
    const float* __restrict__ z, const float* __restrict__ cb,
    const float* __restrict__ cbT, const float* __restrict__ c2,
    float* __restrict__ q, float* __restrict__ partials)
{
    const int row0 = blockIdx.x * 16;
    const int tid  = threadIdx.x;
    const int tr   = tid >> 6;
    const int tk   = tid & 63;

    __shared__ float sZ[16][128];
    __shared__ float sC[32][256];
    __shared__ float sZ2[16];
    __shared__ unsigned long long sKey[16][64];
    __shared__ int   sIdx[16];
    __shared__ float sRed[4];

    for (int idx = tid; idx < 16 * 128; idx += 256)
        sZ[idx >> 7][idx & 127] = z[(size_t)(row0 + (idx >> 7)) * 128 + (idx & 127)];
    __syncthreads();
    if (tid < 16) {
        float s = 0.f;
        for (int e = 0; e < 128; ++e) s = fmaf(sZ[tid][e], sZ[tid][e], s);
        sZ2[tid] = s;
    }
    __syncthreads();

    unsigned long long bk[4] = {~0ull, ~0ull, ~0ull, ~0ull};

    for (int ct = 0; ct < 4; ++ct) {
        float acc[4][4];
#pragma unroll
        for (int i = 0; i < 4; ++i)
#pragma unroll
            for (int j = 0; j < 4; ++j) acc[i][j] = 0.f;

        for (int kt = 0; kt < 4; ++kt) {
            __syncthreads();
            for (int idx = tid; idx < 32 * 256; idx += 256) {
                int e = idx >> 8, c = idx & 255;
                sC[e][c] = cbT[(size_t)(kt * 32 + e) * 1024 + ct * 256 + c];
            }
            __syncthreads();
#pragma unroll 4
            for (int e = 0; e < 32; ++e) {
                float4 cv = *reinterpret_cast<const float4*>(&sC[e][tk << 2]);
                float z0 = sZ[tr * 4 + 0][kt * 32 + e];
                float z1 = sZ[tr * 4 + 1][kt * 32 + e];
                float z2v = sZ[tr * 4 + 2][kt * 32 + e];
                float z3 = sZ[tr * 4 + 3][kt * 32 + e];
                acc[0][0] = fmaf(z0, cv.x, acc[0][0]);
                acc[0][1] = fmaf(z0, cv.y, acc[0][1]);
                acc[0][2] = fmaf(z0, cv.z, acc[0][2]);
                acc[0][3] = fmaf(z0, cv.w, acc[0][3]);
                acc[1][0] = fmaf(z1, cv.x, acc[1][0]);
                acc[1][1] = fmaf(z1, cv.y, acc[1][1]);
                acc[1][2] = fmaf(z1, cv.z, acc[1][2]);
                acc[1][3] = fmaf(z1, cv.w, acc[1][3]);
                acc[2][0] = fmaf(z2v, cv.x, acc[2][0]);
                acc[2][1] = fmaf(z2v, cv.y, acc[2][1]);
                acc[2][2] = fmaf(z2v, cv.z, acc[2][2]);
                acc[2][3] = fmaf(z2v, cv.w, acc[2][3]);
                acc[3][0] = fmaf(z3, cv.x, acc[3][0]);
                acc[3][1] = fmaf(z3, cv.y, acc[3][1]);
                acc[3][2] = fmaf(z3, cv.z, acc[3][2]);
                acc[3][3] = fmaf(z3, cv.w, acc[3][3]);
            }
        }
#pragma unroll
        for (int i = 0; i < 4; ++i) {
            float zz = sZ2[tr * 4 + i];
#pragma unroll
            for (int j = 0; j < 4; ++j) {
                int k = ct * 256 + (tk << 2) + j;
                float d = (zz - 2.0f * acc[i][j]) + c2[k];
                d = fmaxf(d, 0.0f);
                unsigned long long key =
                    ((unsigned long long)__float_as_uint(d) << 32) | (unsigned)k;
                bk[i] = key < bk[i] ? key : bk[i];
            }
        }
    }

#pragma unroll
    for (int i = 0; i < 4; ++i) sKey[tr * 4 + i][tk] = bk[i];
    __syncthreads();
    if (tid < 16) {
        unsigned long long m = sKey[tid][0];
        for (int j = 1; j < 64; ++j) {
            unsigned long long v = sKey[tid][j];
            if (v < m) m = v;
        }
        sIdx[tid] = (int)(m & 0xffffffffull);
    }
    __syncthreads();

    float lsse = 0.f;
    for (int idx = tid; idx < 16 * 128; idx += 256) {
        int r = idx >> 7, e = idx & 127;
        float zv = sZ[r][e];
        float qv = cb[(size_t)sIdx[r] * 128 + e];
        float df = qv - zv;
        lsse = fmaf(df, df, lsse);
        q[(size_t)(row0 + r) * 128 + e] = zv + df;   // z + (q - z)
    }
#pragma unroll
    for (int off = 32; off > 0; off >>= 1) lsse += __shfl_down(lsse, off, 64);
    if (tk == 0) sRed[tr] = lsse;
    __syncthreads();
    if (tid == 0) partials[blockIdx.x] = (sRed[0] + sRed[1]) + (sRed[2] + sRed[3]);
}

// ============================ loss finalize ================================
__global__ __launch_bounds__(256) void loss_finish(
    const float* __restrict__ partials, float* __restrict__ outLoss)
{
    __shared__ float sR[256];
    float s = 0.f;
    for (int i = threadIdx.x; i < 8192; i += 256) s += partials[i];
    sR[threadIdx.x] = s;
    __syncthreads();
    for (int st = 128; st > 0; st >>= 1) {
        if (threadIdx.x < st) sR[threadIdx.x] += sR[threadIdx.x + st];
        __syncthreads();
    }
    if (threadIdx.x == 0) {
        float m = sR[0] / 16777216.0f;          // mean over 8*128*128*128
        outLoss[0] = m + 0.25f * m;             // enc_loss + BETA*com_loss
    }
}

// ============================= launcher ====================================
extern "C" void kernel_launch(void* const* d_in, const int* in_sizes, int n_in,
                              void* d_out, int out_size, void* d_ws, size_t ws_size,
                              hipStream_t stream)
{
    const float* x        = (const float*)d_in[0];
    const float* enc_in_w = (const float*)d_in[1];
    const float* enc_in_b = (const float*)d_in[2];
    const float* rb0_w1   = (const float*)d_in[3];
    const float* rb0_b1   = (const float*)d_in[4];
    const float* rb0_w2   = (const float*)d_in[5];
    const float* rb0_b2   = (const float*)d_in[6];
    const float* rb1_w1   = (const float*)d_in[7];
    const float* rb1_b1   = (const float*)d_in[8];
    const float* rb1_w2   = (const float*)d_in[9];
    const float* rb1_b2   = (const float*)d_in[10];
    const float* rb1_ws   = (const float*)d_in[11];
    const float* rb1_bs   = (const float*)d_in[12];
    const float* down_w   = (const float*)d_in[13];
    const float* down_b   = (const float*)d_in[14];
    const float* codebook = (const float*)d_in[15];
    const float* d1_w1    = (const float*)d_in[16];
    const float* d1_b1    = (const float*)d_in[17];
    const float* d1_w2    = (const float*)d_in[18];
    const float* d1_b2    = (const float*)d_in[19];
    const float* up_w     = (const float*)d_in[20];
    const float* up_b     = (const float*)d_in[21];
    const float* d0_w1    = (const float*)d_in[22];
    const float* d0_b1    = (const float*)d_in[23];
    const float* d0_w2    = (const float*)d_in[24];
    const float* d0_b2    = (const float*)d_in[25];
    const float* out_w    = (const float*)d_in[26];
    const float* out_b    = (const float*)d_in[27];
    (void)in_sizes; (void)n_in; (void)out_size;

    const size_t MB = 1ull << 20;
    char* ws = (char*)d_ws;
    float* partials = (float*)ws;                  // 8192 floats
    float* c2v      = (float*)(ws + 64 * 1024);    // 1024 floats
    float* cbT      = (float*)(ws + 128 * 1024);   // 128x1024 floats (512 KiB)
    char* base = ws + MB;

    // Pick the largest batch chunk whose arena fits ws_size.
    // Arena peak per batch element = 80 MiB (encoder rb1 stage).
    int cb = 8;
    while (cb > 1 && MB + (size_t)cb * 80 * MB > ws_size) cb >>= 1;

    cb_transpose<<<dim3(512), dim3(256), 0, stream>>>(codebook, cbT);
    cb_c2<<<dim3(4), dim3(256), 0, stream>>>(cbT, c2v);

    for (int e0 = 0; e0 < 8; e0 += cb) {
        const float* xc   = x + (size_t)e0 * 3 * 65536;
        float*       outc = (float*)d_out + (size_t)e0 * 3 * 65536;
        float*       pc   = partials + (size_t)e0 * 1024;

        // per-chunk arena (units of MiB * cb):
        float* A  = (float*)(base);                          // h0  [0,16)
        float* B  = (float*)(base + (size_t)cb * 16 * MB);   // t   [16,32)
        float* C  = (float*)(base + (size_t)cb * 32 * MB);   // r0  [32,48)
        float* D  = (float*)(base);                          // t1  [0,32)
        float* E  = (float*)(base + (size_t)cb * 48 * MB);   // r1  [48,80)
        float* Z  = (float*)(base);                          // z   [0,8)
        float* Q  = (float*)(base + (size_t)cb * 8 * MB);    // q   [8,16)
        float* DT = (float*)(base + (size_t)cb * 16 * MB);   // dec rb1 tmp [16,24)
        float* DR = (float*)(base + (size_t)cb * 24 * MB);   // dec rb1 out [24,32)
        float* UP = (float*)(base + (size_t)cb * 32 * MB);   // upsampled   [32,64)
        float* U  = (float*)(base);                          // dec_up out  [0,16)
        float* T2 = (float*)(base + (size_t)cb * 16 * MB);   // dec rb0 tmp [16,32)
        float* R2 = (float*)(base + (size_t)cb * 32 * MB);   // dec rb0 out [32,48)

        // ---------------- encoder ----------------
        conv3x3_s1<false, false><<<dim3(8, 8, cb * 4), 256, 0, stream>>>(
            xc, enc_in_w, enc_in_b, nullptr, A, 3, 64, 256, 256);
        conv3x3_s1<true, false><<<dim3(8, 8, cb * 4), 256, 0, stream>>>(
            A, rb0_w1, rb0_b1, nullptr, B, 64, 64, 256, 256);
        conv3x3_s1<true, true><<<dim3(8, 8, cb * 4), 256, 0, stream>>>(
            B, rb0_w2, rb0_b2, A, C, 64, 64, 256, 256);
        conv3x3_s1<true, false><<<dim3(8, 8, cb * 8), 256, 0, stream>>>(
            C, rb1_w1, rb1_b1, nullptr, D, 64, 128, 256, 256);
        conv1x1<<<dim3(128, cb, 4), 256, 0, stream>>>(
            C, rb1_ws, rb1_bs, E, 64, 128, 65536);
        conv3x3_s1<true, true><<<dim3(8, 8, cb * 8), 256, 0, stream>>>(
            D, rb1_w2, rb1_b2, E, E, 128, 128, 256, 256);   // in-place skip add
        conv3x3_s2<true><<<dim3(4, 8, cb * 8), 256, 0, stream>>>(
            E, down_w, down_b, Z, 128, 128, 256, 256);

        // ---------------- quantizer ----------------
        vq_argmin<<<dim3(cb * 1024), 256, 0, stream>>>(Z, codebook, cbT, c2v, Q, pc);

        // ---------------- decoder ----------------
        conv3x3_s1<true, false><<<dim3(4, 4, cb * 8), 256, 0, stream>>>(
            Q, d1_w1, d1_b1, nullptr, DT, 128, 128, 128, 128);
        conv3x3_s1<true, true><<<dim3(4, 4, cb * 8), 256, 0, stream>>>(
            DT, d1_w2, d1_b2, Q, DR, 128, 128, 128, 128);
        upsample2x<<<dim3(cb * 16384), 256, 0, stream>>>(DR, UP, cb * 128, 128, 128);
        conv3x3_s1<true, false><<<dim3(8, 8, cb * 4), 256, 0, stream>>>(
            UP, up_w, up_b, nullptr, U, 128, 64, 256, 256);
        conv3x3_s1<true, false><<<dim3(8, 8, cb * 4), 256, 0, stream>>>(
            U, d0_w1, d0_b1, nullptr, T2, 64, 64, 256, 256);
        conv3x3_s1<true, true><<<dim3(8, 8, cb * 4), 256, 0, stream>>>(
            T2, d0_w2, d0_b2, U, R2, 64, 64, 256, 256);
        conv3x3_s1<false, false><<<dim3(8, 8, cb * 1), 256, 0, stream>>>(
            R2, out_w, out_b, nullptr, outc, 64, 3, 256, 256);
    }

    // ---------------- loss ----------------
    loss_finish<<<dim3(1), 256, 0, stream>>>(partials, (float*)d_out + 1572864);
}

// Round 3
// 3632.516 us; speedup vs baseline: 4.9390x; 4.9390x over previous
//
#include <hip/hip_runtime.h>

// ---------------------------------------------------------------------------
// VQ-VAE forward: bf16 MFMA implicit-GEMM convs (NHWC), fp32 VQ, fused
// bias/relu/residual epilogues. Batch-chunked arena (56 MiB per batch elem).
// ---------------------------------------------------------------------------

typedef float    f32x4  __attribute__((ext_vector_type(4)));
typedef short    bf16x8 __attribute__((ext_vector_type(8)));
typedef unsigned short ush;

__device__ __forceinline__ ush f2bf(float f) {
    unsigned u = __float_as_uint(f);
    u += 0x7fff + ((u >> 16) & 1);          // round-to-nearest-even
    return (ush)(u >> 16);
}
__device__ __forceinline__ float bf2f(ush h) {
    return __uint_as_float(((unsigned)h) << 16);
}

// ===================== weight repack OIHW f32 -> K-major bf16 ==============
// dst[o][(ky*KS+kx)*I + ci], o padded to Opad with zeros.
__global__ void prep_w(const float* __restrict__ src, ush* __restrict__ dst,
                       int O, int I, int KS, int Opad)
{
    int idx = blockIdx.x * 256 + threadIdx.x;
    int K = KS * KS * I;
    if (idx >= Opad * K) return;
    int o = idx / K, k = idx - o * K;
    float v = 0.f;
    if (o < O) {
        int ci = k % I;
        int kxy = k / I;
        int kx = kxy % KS, ky = kxy / KS;
        v = src[((size_t)(o * I + ci) * KS + ky) * KS + kx];
    }
    dst[idx] = f2bf(v);
}

// ===================== enc_in: 3->64, NCHW f32 in -> NHWC bf16 out =========
// One block per (row y, batch b); 256 threads = 256 pixels; 64 accs/thread.
__global__ __launch_bounds__(256) void enc_in_k(
    const float* __restrict__ x, const float* __restrict__ w,
    const float* __restrict__ bias, ush* __restrict__ out)
{
    __shared__ float sX[3][3][260];   // [cin][row][x+2]
    __shared__ float sW[27][64];
    __shared__ float sB[64];
    const int tid = threadIdx.x;
    const int y = blockIdx.x, b = blockIdx.y;

    for (int i = tid; i < 3 * 3 * 258; i += 256) {
        int xi = i % 258;
        int r  = (i / 258) % 3;
        int c  = i / 774;
        int gy = y + r - 1, gx = xi - 1;
        float v = 0.f;
        if ((unsigned)gy < 256u && (unsigned)gx < 256u)
            v = x[(((size_t)b * 3 + c) * 256 + gy) * 256 + gx];
        sX[c][r][xi] = v;
    }
    for (int i = tid; i < 1728; i += 256) {
        int co = i & 63, k = i >> 6;
        int c = k % 3, kxy = k / 3;
        int kx = kxy % 3, ky = kxy / 3;
        sW[k][co] = w[co * 27 + c * 9 + ky * 3 + kx];
    }
    if (tid < 64) sB[tid] = bias[tid];
    __syncthreads();

    float acc[64];
#pragma unroll
    for (int c = 0; c < 64; ++c) acc[c] = 0.f;
    const int px = tid;
#pragma unroll
    for (int k = 0; k < 27; ++k) {
        const int c = k % 3, kxy = k / 3;
        const int kx = kxy % 3, ky = kxy / 3;
        float iv = sX[c][ky][px + kx];
#pragma unroll
        for (int co = 0; co < 64; ++co) acc[co] = fmaf(iv, sW[k][co], acc[co]);
    }
    ush* op = out + (((size_t)b * 256 + y) * 256 + px) * 64;
#pragma unroll
    for (int c8 = 0; c8 < 8; ++c8) {
        ush tmp[8];
#pragma unroll
        for (int j = 0; j < 8; ++j) tmp[j] = f2bf(acc[c8 * 8 + j] + sB[c8 * 8 + j]);
        *(int4*)(op + c8 * 8) = *(const int4*)tmp;
    }
}

// ===================== MFMA conv, stride 1, NHWC bf16 ======================
// Block: 64 cout x 64 px (one row), 4 waves (2x2). K staged entirely in LDS.
template<int CIN, int COUT, int KS, bool RELU, bool ADD>
__global__ __launch_bounds__(256) void mconv(
    const ush* __restrict__ in, const ush* __restrict__ wt,
    const float* __restrict__ bias, const ush* __restrict__ res,
    ush* __restrict__ out, int H, int W)
{
    constexpr int HALO = KS / 2;
    constexpr int XW   = 64 + 2 * HALO;
    constexpr int K    = KS * KS * CIN;
    constexpr int K32  = K / 32;
    constexpr int COB  = COUT / 64;

    __shared__ ush sIn[KS * XW * CIN];

    const int tid = threadIdx.x;
    const int b   = blockIdx.z / COB;
    const int co0 = (blockIdx.z % COB) * 64;
    const int y   = blockIdx.y;
    const int x0  = blockIdx.x * 64;

    constexpr int CHUNKS = KS * XW * CIN / 8;
    for (int i = tid; i < CHUNKS; i += 256) {
        int ci8 = i % (CIN / 8);
        int r2  = i / (CIN / 8);
        int xi  = r2 % XW;
        int row = r2 / XW;
        int gy = y + row - HALO;
        int gx = x0 + xi - HALO;
        int4 v = make_int4(0, 0, 0, 0);
        if ((unsigned)gy < (unsigned)H && (unsigned)gx < (unsigned)W)
            v = *(const int4*)(in + (((size_t)b * H + gy) * W + gx) * CIN + ci8 * 8);
        int bo = ((row * XW + xi) * CIN + ci8 * 8) * 2;
        *(int4*)((char*)sIn + (bo ^ ((xi & 7) << 4))) = v;
    }
    __syncthreads();

    const int lane = tid & 63, wid = tid >> 6;
    const int wm = wid >> 1, wn = wid & 1;
    const int l15 = lane & 15, lq = lane >> 4;

    f32x4 acc[2][2] = {};
    const ush* wp  = wt + (size_t)(co0 + wm * 32 + l15) * K + lq * 8;
    const ush* wp2 = wp + 16 * K;
    const int bbase = (wn * 32 + l15) * CIN * 2 + lq * 16;

#pragma unroll
    for (int kb = 0; kb < K32; ++kb) {
        const int k0  = kb * 32;
        const int ci0 = k0 % CIN;
        const int kxy = k0 / CIN;
        const int kx = kxy % KS, ky = kxy / KS;
        bf16x8 a0 = *(const bf16x8*)(wp  + k0);
        bf16x8 a1 = *(const bf16x8*)(wp2 + k0);
        const int xl0 = wn * 32 + l15 + kx;
        const int bo0 = bbase + ((ky * XW + kx) * CIN + ci0) * 2;
        bf16x8 b0 = *(const bf16x8*)((const char*)sIn + (bo0 ^ ((xl0 & 7) << 4)));
        const int xl1 = xl0 + 16;
        const int bo1 = bo0 + 16 * CIN * 2;
        bf16x8 b1 = *(const bf16x8*)((const char*)sIn + (bo1 ^ ((xl1 & 7) << 4)));
        acc[0][0] = __builtin_amdgcn_mfma_f32_16x16x32_bf16(a0, b0, acc[0][0], 0, 0, 0);
        acc[0][1] = __builtin_amdgcn_mfma_f32_16x16x32_bf16(a0, b1, acc[0][1], 0, 0, 0);
        acc[1][0] = __builtin_amdgcn_mfma_f32_16x16x32_bf16(a1, b0, acc[1][0], 0, 0, 0);
        acc[1][1] = __builtin_amdgcn_mfma_f32_16x16x32_bf16(a1, b1, acc[1][1], 0, 0, 0);
    }

#pragma unroll
    for (int m = 0; m < 2; ++m) {
        const int com = co0 + wm * 32 + m * 16 + lq * 4;
        float4 bv = *(const float4*)(bias + com);
#pragma unroll
        for (int n = 0; n < 2; ++n) {
            const int px = x0 + wn * 32 + n * 16 + l15;
            size_t oaddr = (((size_t)b * H + y) * W + px) * COUT + com;
            float v0 = acc[m][n][0] + bv.x;
            float v1 = acc[m][n][1] + bv.y;
            float v2 = acc[m][n][2] + bv.z;
            float v3 = acc[m][n][3] + bv.w;
            if constexpr (ADD) {
                ushort4 rv = *(const ushort4*)(res + oaddr);
                v0 += bf2f(rv.x); v1 += bf2f(rv.y);
                v2 += bf2f(rv.z); v3 += bf2f(rv.w);
            }
            if constexpr (RELU) {
                v0 = fmaxf(v0, 0.f); v1 = fmaxf(v1, 0.f);
                v2 = fmaxf(v2, 0.f); v3 = fmaxf(v3, 0.f);
            }
            ushort4 o;
            o.x = f2bf(v0); o.y = f2bf(v1); o.z = f2bf(v2); o.w = f2bf(v3);
            *(ushort4*)(out + oaddr) = o;
        }
    }
}

// ============ MFMA conv 3x3 stride 2 (128->128), out z NCHW fp32 ===========
__global__ __launch_bounds__(256) void mconv_s2_z(
    const ush* __restrict__ in, const ush* __restrict__ wt,
    const float* __restrict__ bias, float* __restrict__ zout, int Hi, int Wi)
{
    constexpr int CIN = 128, COUT = 128, K = 1152, K32 = 36, XW = 66;
    __shared__ ush sIn[3 * XW * CIN];
    const int Ho = Hi >> 1, Wo = Wi >> 1;
    const int tid = threadIdx.x;
    const int b = blockIdx.z >> 1, co0 = (blockIdx.z & 1) * 64;
    const int yo = blockIdx.y, xo0 = blockIdx.x * 32;

    for (int i = tid; i < 3 * XW * CIN / 8; i += 256) {
        int ci8 = i & 15;
        int r2  = i >> 4;
        int xi  = r2 % XW;
        int row = r2 / XW;
        int gy = 2 * yo + row - 1, gx = 2 * xo0 + xi - 1;
        int4 v = make_int4(0, 0, 0, 0);
        if ((unsigned)gy < (unsigned)Hi && (unsigned)gx < (unsigned)Wi)
            v = *(const int4*)(in + (((size_t)b * Hi + gy) * Wi + gx) * CIN + ci8 * 8);
        int bo = ((row * XW + xi) * CIN + ci8 * 8) * 2;
        *(int4*)((char*)sIn + (bo ^ ((xi & 7) << 4))) = v;
    }
    __syncthreads();

    const int lane = tid & 63, wid = tid >> 6;
    const int wm = wid >> 1, wn = wid & 1;
    const int l15 = lane & 15, lq = lane >> 4;

    f32x4 acc[2] = {};
    const ush* wp  = wt + (size_t)(co0 + wm * 32 + l15) * K + lq * 8;
    const ush* wp2 = wp + 16 * K;
    const int pxl = wn * 16 + l15;

#pragma unroll
    for (int kb = 0; kb < K32; ++kb) {
        const int k0 = kb * 32;
        const int ci0 = k0 % CIN;
        const int kxy = k0 / CIN;
        const int kx = kxy % 3, ky = kxy / 3;
        bf16x8 a0 = *(const bf16x8*)(wp  + k0);
        bf16x8 a1 = *(const bf16x8*)(wp2 + k0);
        const int xl = 2 * pxl + kx;
        const int bo = ((ky * XW + xl) * CIN + ci0 + lq * 8) * 2;
        bf16x8 bfr = *(const bf16x8*)((const char*)sIn + (bo ^ ((xl & 7) << 4)));
        acc[0] = __builtin_amdgcn_mfma_f32_16x16x32_bf16(a0, bfr, acc[0], 0, 0, 0);
        acc[1] = __builtin_amdgcn_mfma_f32_16x16x32_bf16(a1, bfr, acc[1], 0, 0, 0);
    }

    const int px = xo0 + pxl;
#pragma unroll
    for (int m = 0; m < 2; ++m) {
        const int com = co0 + wm * 32 + m * 16 + lq * 4;
        float4 bv = *(const float4*)(bias + com);
#pragma unroll
        for (int r = 0; r < 4; ++r) {
            float v = acc[m][r] + ((const float*)&bv)[r];
            v = fmaxf(v, 0.f);
            zout[(((size_t)b * COUT + com + r) * Ho + yo) * Wo + px] = v;
        }
    }
}

// ============ final conv 64->3, NHWC bf16 in -> NCHW f32 d_out =============
__global__ __launch_bounds__(256) void mconv_out(
    const ush* __restrict__ in, const ush* __restrict__ wt,
    const float* __restrict__ bias, float* __restrict__ outv, int H, int W)
{
    constexpr int K = 576, K32 = 18, XW = 130;
    __shared__ ush sIn[3 * XW * 64];
    const int tid = threadIdx.x;
    const int b = blockIdx.z, y = blockIdx.y, x0 = blockIdx.x * 128;

    for (int i = tid; i < 3 * XW * 64 / 8; i += 256) {
        int ci8 = i & 7;
        int r2  = i >> 3;
        int xi  = r2 % XW;
        int row = r2 / XW;
        int gy = y + row - 1, gx = x0 + xi - 1;
        int4 v = make_int4(0, 0, 0, 0);
        if ((unsigned)gy < (unsigned)H && (unsigned)gx < (unsigned)W)
            v = *(const int4*)(in + (((size_t)b * H + gy) * W + gx) * 64 + ci8 * 8);
        int bo = ((row * XW + xi) * 64 + ci8 * 8) * 2;
        *(int4*)((char*)sIn + (bo ^ ((xi & 7) << 4))) = v;
    }
    __syncthreads();

    const int lane = tid & 63, wid = tid >> 6;
    const int l15 = lane & 15, lq = lane >> 4;

    f32x4 acc[2] = {};
    const ush* wp = wt + (size_t)l15 * K + lq * 8;

#pragma unroll
    for (int kb = 0; kb < K32; ++kb) {
        const int k0 = kb * 32;
        const int ci0 = k0 % 64;
        const int kxy = k0 / 64;
        const int kx = kxy % 3, ky = kxy / 3;
        bf16x8 a0 = *(const bf16x8*)(wp + k0);
#pragma unroll
        for (int n = 0; n < 2; ++n) {
            const int xl = wid * 32 + n * 16 + l15 + kx;
            const int bo = ((ky * XW + xl) * 64 + ci0 + lq * 8) * 2;
            bf16x8 bfr = *(const bf16x8*)((const char*)sIn + (bo ^ ((xl & 7) << 4)));
            acc[n] = __builtin_amdgcn_mfma_f32_16x16x32_bf16(a0, bfr, acc[n], 0, 0, 0);
        }
    }

#pragma unroll
    for (int n = 0; n < 2; ++n) {
        const int px = x0 + wid * 32 + n * 16 + l15;
        if (lq == 0) {
#pragma unroll
            for (int r = 0; r < 3; ++r)
                outv[(((size_t)b * 3 + r) * H + y) * W + px] = acc[n][r] + bias[r];
        }
    }
}

// ============== q transpose: NCHW bf16 -> NHWC bf16 (C=H=W=128) ============
__global__ __launch_bounds__(256) void transpose_q(
    const ush* __restrict__ qc, ush* __restrict__ qh)
{
    __shared__ ush sT[128][136];
    const int tid = threadIdx.x;
    const int b = blockIdx.x >> 7, h = blockIdx.x & 127;

    for (int i = tid; i < 2048; i += 256) {
        int c = i >> 4, w8 = i & 15;
        int4 v = *(const int4*)(qc + (((size_t)b * 128 + c) * 128 + h) * 128 + w8 * 8);
        const ush* pv = (const ush*)&v;
#pragma unroll
        for (int j = 0; j < 8; ++j) sT[w8 * 8 + j][c] = pv[j];
    }
    __syncthreads();
    for (int i = tid; i < 2048; i += 256) {
        int w = i >> 4, c8 = i & 15;
        int4 v;
        ush* pv = (ush*)&v;
#pragma unroll
        for (int j = 0; j < 8; ++j) pv[j] = sT[w][c8 * 8 + j];
        *(int4*)(qh + (((size_t)b * 128 + h) * 128 + w) * 128 + c8 * 8) = v;
    }
}

// ================= nearest 2x upsample, NHWC bf16 (C=128) ==================
__global__ void upsample2x_nhwc(const ush* __restrict__ in, ush* __restrict__ out)
{
    // out (b,256,256,128); one int4 (8ch) per thread
    long idx = (long)blockIdx.x * 256 + threadIdx.x;
    int c8 = (int)(idx & 15);
    int xx = (int)((idx >> 4) & 255);
    int yy = (int)((idx >> 12) & 255);
    int b  = (int)(idx >> 20);
    int4 v = *(const int4*)(in + (((size_t)b * 128 + (yy >> 1)) * 128 + (xx >> 1)) * 128 + c8 * 8);
    *(int4*)(out + (((size_t)b * 256 + yy) * 256 + xx) * 128 + c8 * 8) = v;
}

// ========================= codebook preparation ============================
__global__ void cb_transpose(const float* __restrict__ cb, float* __restrict__ cbT)
{
    int idx = blockIdx.x * 256 + threadIdx.x;
    if (idx < 1024 * 128) {
        int k = idx >> 7, e = idx & 127;
        cbT[e * 1024 + k] = cb[idx];
    }
}

__global__ void cb_c2(const float* __restrict__ cbT, float* __restrict__ c2)
{
    int k = blockIdx.x * 256 + threadIdx.x;
    if (k < 1024) {
        float s = 0.f;
        for (int e = 0; e < 128; ++e) {
            float v = cbT[e * 1024 + k];
            s = fmaf(v, v, s);
        }
        c2[k] = s;
    }
}

// ============================== quantizer ==================================
// z NCHW fp32 in; q NCHW bf16 out; sse partials out. Faithful expanded-form d.
__global__ __launch_bounds__(256) void vq_argmin(
    const float* __restrict__ z, const float* __restrict__ cb,
    const float* __restrict__ cbT, const float* __restrict__ c2,
    ush* __restrict__ q, float* __restrict__ partials)
{
    const int row0 = blockIdx.x * 16;
    const int tid  = threadIdx.x;
    const int tr   = tid >> 6;
    const int tk   = tid & 63;

    __shared__ float sZ[16][128];
    __shared__ float sC[32][256];
    __shared__ float sZ2[16];
    __shared__ unsigned long long sKey[16][64];
    __shared__ int   sIdx[16];
    __shared__ float sRed[4];

    for (int idx = tid; idx < 16 * 128; idx += 256)
        sZ[idx >> 7][idx & 127] = z[(size_t)(row0 + (idx >> 7)) * 128 + (idx & 127)];
    __syncthreads();
    if (tid < 16) {
        float s = 0.f;
        for (int e = 0; e < 128; ++e) s = fmaf(sZ[tid][e], sZ[tid][e], s);
        sZ2[tid] = s;
    }
    __syncthreads();

    unsigned long long bk[4] = {~0ull, ~0ull, ~0ull, ~0ull};

    for (int ct = 0; ct < 4; ++ct) {
        float acc[4][4];
#pragma unroll
        for (int i = 0; i < 4; ++i)
#pragma unroll
            for (int j = 0; j < 4; ++j) acc[i][j] = 0.f;

        for (int kt = 0; kt < 4; ++kt) {
            __syncthreads();
            for (int idx = tid; idx < 32 * 256; idx += 256) {
                int e = idx >> 8, c = idx & 255;
                sC[e][c] = cbT[(size_t)(kt * 32 + e) * 1024 + ct * 256 + c];
            }
            __syncthreads();
#pragma unroll 4
            for (int e = 0; e < 32; ++e) {
                float4 cv = *reinterpret_cast<const float4*>(&sC[e][tk << 2]);
                float z0 = sZ[tr * 4 + 0][kt * 32 + e];
                float z1 = sZ[tr * 4 + 1][kt * 32 + e];
                float z2v = sZ[tr * 4 + 2][kt * 32 + e];
                float z3 = sZ[tr * 4 + 3][kt * 32 + e];
                acc[0][0] = fmaf(z0, cv.x, acc[0][0]);
                acc[0][1] = fmaf(z0, cv.y, acc[0][1]);
                acc[0][2] = fmaf(z0, cv.z, acc[0][2]);
                acc[0][3] = fmaf(z0, cv.w, acc[0][3]);
                acc[1][0] = fmaf(z1, cv.x, acc[1][0]);
                acc[1][1] = fmaf(z1, cv.y, acc[1][1]);
                acc[1][2] = fmaf(z1, cv.z, acc[1][2]);
                acc[1][3] = fmaf(z1, cv.w, acc[1][3]);
                acc[2][0] = fmaf(z2v, cv.x, acc[2][0]);
                acc[2][1] = fmaf(z2v, cv.y, acc[2][1]);
                acc[2][2] = fmaf(z2v, cv.z, acc[2][2]);
                acc[2][3] = fmaf(z2v, cv.w, acc[2][3]);
                acc[3][0] = fmaf(z3, cv.x, acc[3][0]);
                acc[3][1] = fmaf(z3, cv.y, acc[3][1]);
                acc[3][2] = fmaf(z3, cv.z, acc[3][2]);
                acc[3][3] = fmaf(z3, cv.w, acc[3][3]);
            }
        }
#pragma unroll
        for (int i = 0; i < 4; ++i) {
            float zz = sZ2[tr * 4 + i];
#pragma unroll
            for (int j = 0; j < 4; ++j) {
                int k = ct * 256 + (tk << 2) + j;
                float d = (zz - 2.0f * acc[i][j]) + c2[k];
                d = fmaxf(d, 0.0f);
                unsigned long long key =
                    ((unsigned long long)__float_as_uint(d) << 32) | (unsigned)k;
                bk[i] = key < bk[i] ? key : bk[i];
            }
        }
    }

#pragma unroll
    for (int i = 0; i < 4; ++i) sKey[tr * 4 + i][tk] = bk[i];
    __syncthreads();
    if (tid < 16) {
        unsigned long long m = sKey[tid][0];
        for (int j = 1; j < 64; ++j) {
            unsigned long long v = sKey[tid][j];
            if (v < m) m = v;
        }
        sIdx[tid] = (int)(m & 0xffffffffull);
    }
    __syncthreads();

    float lsse = 0.f;
    for (int idx = tid; idx < 16 * 128; idx += 256) {
        int r = idx >> 7, e = idx & 127;
        float zv = sZ[r][e];
        float qv = cb[(size_t)sIdx[r] * 128 + e];
        float df = qv - zv;
        lsse = fmaf(df, df, lsse);
        q[(size_t)(row0 + r) * 128 + e] = f2bf(zv + df);   // z + (q - z)
    }
#pragma unroll
    for (int off = 32; off > 0; off >>= 1) lsse += __shfl_down(lsse, off, 64);
    if (tk == 0) sRed[tr] = lsse;
    __syncthreads();
    if (tid == 0) partials[blockIdx.x] = (sRed[0] + sRed[1]) + (sRed[2] + sRed[3]);
}

// ============================ loss finalize ================================
__global__ __launch_bounds__(256) void loss_finish(
    const float* __restrict__ partials, float* __restrict__ outLoss)
{
    __shared__ float sR[256];
    float s = 0.f;
    for (int i = threadIdx.x; i < 8192; i += 256) s += partials[i];
    sR[threadIdx.x] = s;
    __syncthreads();
    for (int st = 128; st > 0; st >>= 1) {
        if (threadIdx.x < st) sR[threadIdx.x] += sR[threadIdx.x + st];
        __syncthreads();
    }
    if (threadIdx.x == 0) {
        float m = sR[0] / 16777216.0f;
        outLoss[0] = m + 0.25f * m;
    }
}

// ============================= launcher ====================================
extern "C" void kernel_launch(void* const* d_in, const int* in_sizes, int n_in,
                              void* d_out, int out_size, void* d_ws, size_t ws_size,
                              hipStream_t stream)
{
    const float* x        = (const float*)d_in[0];
    const float* enc_in_w = (const float*)d_in[1];
    const float* enc_in_b = (const float*)d_in[2];
    const float* rb0_w1   = (const float*)d_in[3];
    const float* rb0_b1   = (const float*)d_in[4];
    const float* rb0_w2   = (const float*)d_in[5];
    const float* rb0_b2   = (const float*)d_in[6];
    const float* rb1_w1   = (const float*)d_in[7];
    const float* rb1_b1   = (const float*)d_in[8];
    const float* rb1_w2   = (const float*)d_in[9];
    const float* rb1_b2   = (const float*)d_in[10];
    const float* rb1_ws   = (const float*)d_in[11];
    const float* rb1_bs   = (const float*)d_in[12];
    const float* down_w   = (const float*)d_in[13];
    const float* down_b   = (const float*)d_in[14];
    const float* codebook = (const float*)d_in[15];
    const float* d1_w1    = (const float*)d_in[16];
    const float* d1_b1    = (const float*)d_in[17];
    const float* d1_w2    = (const float*)d_in[18];
    const float* d1_b2    = (const float*)d_in[19];
    const float* up_w     = (const float*)d_in[20];
    const float* up_b     = (const float*)d_in[21];
    const float* d0_w1    = (const float*)d_in[22];
    const float* d0_b1    = (const float*)d_in[23];
    const float* d0_w2    = (const float*)d_in[24];
    const float* d0_b2    = (const float*)d_in[25];
    const float* out_w    = (const float*)d_in[26];
    const float* out_b    = (const float*)d_in[27];
    (void)in_sizes; (void)n_in; (void)out_size;

    const size_t MB = 1ull << 20;
    char* ws = (char*)d_ws;
    float* partials = (float*)ws;                  // 8192 f32
    float* c2v      = (float*)(ws + 64 * 1024);    // 1024 f32
    float* cbT      = (float*)(ws + 128 * 1024);   // 128x1024 f32
    ush*   wreg     = (ush*)(ws + 1 * MB);         // packed bf16 weights

    // packed-weight offsets (ushort units)
    ush* w_rb0_1 = wreg + 0;
    ush* w_rb0_2 = wreg + 36864;
    ush* w_rb1_1 = wreg + 73728;
    ush* w_rb1_2 = wreg + 147456;
    ush* w_rb1_s = wreg + 294912;
    ush* w_down  = wreg + 303104;
    ush* w_d1_1  = wreg + 450560;
    ush* w_d1_2  = wreg + 598016;
    ush* w_up    = wreg + 745472;
    ush* w_d0_1  = wreg + 819200;
    ush* w_d0_2  = wreg + 856064;
    ush* w_out   = wreg + 892928;

    char* base = ws + 4 * MB;

    int cbn = 8;
    while (cbn > 1 && 4 * MB + (size_t)cbn * 56 * MB > ws_size) cbn >>= 1;

    auto prep = [&](const float* src, ush* dst, int O, int I, int KSp, int Opad) {
        int tot = Opad * KSp * KSp * I;
        prep_w<<<dim3((tot + 255) / 256), 256, 0, stream>>>(src, dst, O, I, KSp, Opad);
    };
    prep(rb0_w1, w_rb0_1, 64, 64, 3, 64);
    prep(rb0_w2, w_rb0_2, 64, 64, 3, 64);
    prep(rb1_w1, w_rb1_1, 128, 64, 3, 128);
    prep(rb1_w2, w_rb1_2, 128, 128, 3, 128);
    prep(rb1_ws, w_rb1_s, 128, 64, 1, 128);
    prep(down_w, w_down, 128, 128, 3, 128);
    prep(d1_w1, w_d1_1, 128, 128, 3, 128);
    prep(d1_w2, w_d1_2, 128, 128, 3, 128);
    prep(up_w, w_up, 64, 128, 3, 64);
    prep(d0_w1, w_d0_1, 64, 64, 3, 64);
    prep(d0_w2, w_d0_2, 64, 64, 3, 64);
    prep(out_w, w_out, 3, 64, 3, 16);

    cb_transpose<<<dim3(512), 256, 0, stream>>>(codebook, cbT);
    cb_c2<<<dim3(4), 256, 0, stream>>>(cbT, c2v);

    for (int e0 = 0; e0 < 8; e0 += cbn) {
        const float* xc   = x + (size_t)e0 * 3 * 65536;
        float*       outc = (float*)d_out + (size_t)e0 * 3 * 65536;
        float*       pc   = partials + (size_t)e0 * 1024;

        // arena (per-elem MiB offsets x cbn)
        ush*   h0 = (ush*)(base + (size_t)cbn * 0 * MB);
        ush*   t  = (ush*)(base + (size_t)cbn * 8 * MB);
        ush*   r0 = (ush*)(base + (size_t)cbn * 16 * MB);
        ush*   t1 = (ush*)(base + (size_t)cbn * 24 * MB);
        ush*   r1 = (ush*)(base + (size_t)cbn * 40 * MB);
        float* z  = (float*)(base + (size_t)cbn * 0 * MB);
        ush*   qc = (ush*)(base + (size_t)cbn * 8 * MB);
        ush*   qh = (ush*)(base + (size_t)cbn * 12 * MB);
        ush*   dt = (ush*)(base + (size_t)cbn * 16 * MB);
        ush*   dr = (ush*)(base + (size_t)cbn * 20 * MB);
        ush*   up = (ush*)(base + (size_t)cbn * 24 * MB);
        ush*   u  = (ush*)(base + (size_t)cbn * 40 * MB);
        ush*   t2 = (ush*)(base + (size_t)cbn * 0 * MB);
        ush*   r2 = (ush*)(base + (size_t)cbn * 8 * MB);

        // ---------------- encoder ----------------
        enc_in_k<<<dim3(256, cbn), 256, 0, stream>>>(xc, enc_in_w, enc_in_b, h0);
        mconv<64, 64, 3, true, false><<<dim3(4, 256, cbn), 256, 0, stream>>>(
            h0, w_rb0_1, rb0_b1, nullptr, t, 256, 256);
        mconv<64, 64, 3, true, true><<<dim3(4, 256, cbn), 256, 0, stream>>>(
            t, w_rb0_2, rb0_b2, h0, r0, 256, 256);
        mconv<64, 128, 3, true, false><<<dim3(4, 256, 2 * cbn), 256, 0, stream>>>(
            r0, w_rb1_1, rb1_b1, nullptr, t1, 256, 256);
        mconv<64, 128, 1, false, false><<<dim3(4, 256, 2 * cbn), 256, 0, stream>>>(
            r0, w_rb1_s, rb1_bs, nullptr, r1, 256, 256);
        mconv<128, 128, 3, true, true><<<dim3(4, 256, 2 * cbn), 256, 0, stream>>>(
            t1, w_rb1_2, rb1_b2, r1, r1, 256, 256);
        mconv_s2_z<<<dim3(4, 128, 2 * cbn), 256, 0, stream>>>(
            r1, w_down, down_b, z, 256, 256);

        // ---------------- quantizer ----------------
        vq_argmin<<<dim3(cbn * 1024), 256, 0, stream>>>(z, codebook, cbT, c2v, qc, pc);
        transpose_q<<<dim3(cbn * 128), 256, 0, stream>>>(qc, qh);

        // ---------------- decoder ----------------
        mconv<128, 128, 3, true, false><<<dim3(2, 128, 2 * cbn), 256, 0, stream>>>(
            qh, w_d1_1, d1_b1, nullptr, dt, 128, 128);
        mconv<128, 128, 3, true, true><<<dim3(2, 128, 2 * cbn), 256, 0, stream>>>(
            dt, w_d1_2, d1_b2, qh, dr, 128, 128);
        upsample2x_nhwc<<<dim3(cbn * 4096), 256, 0, stream>>>(dr, up);
        mconv<128, 64, 3, true, false><<<dim3(4, 256, cbn), 256, 0, stream>>>(
            up, w_up, up_b, nullptr, u, 256, 256);
        mconv<64, 64, 3, true, false><<<dim3(4, 256, cbn), 256, 0, stream>>>(
            u, w_d0_1, d0_b1, nullptr, t2, 256, 256);
        mconv<64, 64, 3, true, true><<<dim3(4, 256, cbn), 256, 0, stream>>>(
            t2, w_d0_2, d0_b2, u, r2, 256, 256);
        mconv_out<<<dim3(2, 256, cbn), 256, 0, stream>>>(
            r2, w_out, out_b, outc, 256, 256);
    }

    // ---------------- loss ----------------
    loss_finish<<<dim3(1), 256, 0, stream>>>(partials, (float*)d_out + 1572864);
}

// Round 4
// 3426.822 us; speedup vs baseline: 5.2355x; 1.0600x over previous
//
#include <hip/hip_runtime.h>

// ---------------------------------------------------------------------------
// VQ-VAE forward: bf16 MFMA implicit-GEMM convs (NHWC), fp32 VQ, fused
// bias/relu/residual epilogues. Multi-row conv blocks w/ A-hoisted K-loop.
// ---------------------------------------------------------------------------

typedef float    f32x4  __attribute__((ext_vector_type(4)));
typedef short    bf16x8 __attribute__((ext_vector_type(8)));
typedef unsigned short ush;

__device__ __forceinline__ ush f2bf(float f) {
    unsigned u = __float_as_uint(f);
    u += 0x7fff + ((u >> 16) & 1);          // round-to-nearest-even
    return (ush)(u >> 16);
}
__device__ __forceinline__ float bf2f(ush h) {
    return __uint_as_float(((unsigned)h) << 16);
}

// ===================== weight repack OIHW f32 -> K-major bf16 ==============
__global__ void prep_w(const float* __restrict__ src, ush* __restrict__ dst,
                       int O, int I, int KS, int Opad)
{
    int idx = blockIdx.x * 256 + threadIdx.x;
    int K = KS * KS * I;
    if (idx >= Opad * K) return;
    int o = idx / K, k = idx - o * K;
    float v = 0.f;
    if (o < O) {
        int ci = k % I;
        int kxy = k / I;
        int kx = kxy % KS, ky = kxy / KS;
        v = src[((size_t)(o * I + ci) * KS + ky) * KS + kx];
    }
    dst[idx] = f2bf(v);
}

// ===================== enc_in: 3->64, NCHW f32 in -> NHWC bf16 out =========
__global__ __launch_bounds__(256) void enc_in_k(
    const float* __restrict__ x, const float* __restrict__ w,
    const float* __restrict__ bias, ush* __restrict__ out)
{
    __shared__ float sX[3][3][260];
    __shared__ float sW[27][64];
    __shared__ float sB[64];
    const int tid = threadIdx.x;
    const int y = blockIdx.x, b = blockIdx.y;

    for (int i = tid; i < 3 * 3 * 258; i += 256) {
        int xi = i % 258;
        int r  = (i / 258) % 3;
        int c  = i / 774;
        int gy = y + r - 1, gx = xi - 1;
        float v = 0.f;
        if ((unsigned)gy < 256u && (unsigned)gx < 256u)
            v = x[(((size_t)b * 3 + c) * 256 + gy) * 256 + gx];
        sX[c][r][xi] = v;
    }
    for (int i = tid; i < 1728; i += 256) {
        int co = i & 63, k = i >> 6;
        int c = k % 3, kxy = k / 3;
        int kx = kxy % 3, ky = kxy / 3;
        sW[k][co] = w[co * 27 + c * 9 + ky * 3 + kx];
    }
    if (tid < 64) sB[tid] = bias[tid];
    __syncthreads();

    float acc[64];
#pragma unroll
    for (int c = 0; c < 64; ++c) acc[c] = 0.f;
    const int px = tid;
#pragma unroll
    for (int k = 0; k < 27; ++k) {
        const int c = k % 3, kxy = k / 3;
        const int kx = kxy % 3, ky = kxy / 3;
        float iv = sX[c][ky][px + kx];
#pragma unroll
        for (int co = 0; co < 64; ++co) acc[co] = fmaf(iv, sW[k][co], acc[co]);
    }
    ush* op = out + (((size_t)b * 256 + y) * 256 + px) * 64;
#pragma unroll
    for (int c8 = 0; c8 < 8; ++c8) {
        ush tmp[8];
#pragma unroll
        for (int j = 0; j < 8; ++j) tmp[j] = f2bf(acc[c8 * 8 + j] + sB[c8 * 8 + j]);
        *(int4*)(op + c8 * 8) = *(const int4*)tmp;
    }
}

// ===================== MFMA conv, stride 1, NHWC bf16 ======================
// Block: 64 cout x 64 px x ROWS rows, 4 waves. A-loads hoisted; B from LDS.
// ROWS=4 (CIN<=64): wave = one row, acc[4][4].  ROWS=2 (CIN=128): wave =
// (row, px-half), acc[4][2].
template<int CIN, int COUT, int KS, int ROWS, bool RELU, bool ADD>
__global__ __launch_bounds__(256) void mconv(
    const ush* __restrict__ in, const ush* __restrict__ wt,
    const float* __restrict__ bias, const ush* __restrict__ res,
    ush* __restrict__ out, int H, int W)
{
    constexpr int HALO  = KS / 2;
    constexpr int XW    = 64 + 2 * HALO;
    constexpr int K     = KS * KS * CIN;
    constexpr int K32   = K / 32;
    constexpr int COB   = COUT / 64;
    constexpr int SROWS = ROWS + 2 * HALO;
    constexpr int F     = ROWS;        // px fragments per wave
    constexpr int WPR   = 4 / ROWS;    // waves per row

    __shared__ ush sIn[SROWS * XW * CIN];

    const int tid = threadIdx.x;
    const int b   = blockIdx.z / COB;
    const int co0 = (blockIdx.z % COB) * 64;
    const int y0  = blockIdx.y * ROWS;
    const int x0  = blockIdx.x * 64;

    constexpr int CHUNKS = SROWS * XW * CIN / 8;
    for (int i = tid; i < CHUNKS; i += 256) {
        int ci8 = i % (CIN / 8);
        int r2  = i / (CIN / 8);
        int xi  = r2 % XW;
        int row = r2 / XW;
        int gy = y0 + row - HALO;
        int gx = x0 + xi - HALO;
        int4 v = make_int4(0, 0, 0, 0);
        if ((unsigned)gy < (unsigned)H && (unsigned)gx < (unsigned)W)
            v = *(const int4*)(in + (((size_t)b * H + gy) * W + gx) * CIN + ci8 * 8);
        int bo = ((row * XW + xi) * CIN + ci8 * 8) * 2;
        *(int4*)((char*)sIn + (bo ^ ((xi & 7) << 4))) = v;
    }
    __syncthreads();

    const int lane = tid & 63, wid = tid >> 6;
    const int r   = wid / WPR;
    const int fb  = (wid % WPR) * F;
    const int l15 = lane & 15, lq = lane >> 4;

    f32x4 acc[4][F] = {};
    const ush* wp = wt + (size_t)(co0 + l15) * K + lq * 8;

#pragma unroll
    for (int kb = 0; kb < K32; ++kb) {
        const int k0  = kb * 32;
        const int ci0 = k0 % CIN;
        const int kxy = k0 / CIN;
        const int kx = kxy % KS, ky = kxy / KS;
        bf16x8 a[4];
#pragma unroll
        for (int m = 0; m < 4; ++m)
            a[m] = *(const bf16x8*)(wp + (size_t)m * 16 * K + k0);
#pragma unroll
        for (int n = 0; n < F; ++n) {
            const int xi = (fb + n) * 16 + l15 + kx;
            const int bo = (((r + ky) * XW + xi) * CIN + ci0 + lq * 8) * 2;
            bf16x8 bv = *(const bf16x8*)((const char*)sIn + (bo ^ ((xi & 7) << 4)));
#pragma unroll
            for (int m = 0; m < 4; ++m)
                acc[m][n] = __builtin_amdgcn_mfma_f32_16x16x32_bf16(a[m], bv, acc[m][n], 0, 0, 0);
        }
    }

    const int y = y0 + r;
#pragma unroll
    for (int m = 0; m < 4; ++m) {
        const int com = co0 + m * 16 + lq * 4;
        float4 bvv = *(const float4*)(bias + com);
#pragma unroll
        for (int n = 0; n < F; ++n) {
            const int px = x0 + (fb + n) * 16 + l15;
            size_t oaddr = (((size_t)b * H + y) * W + px) * COUT + com;
            float v0 = acc[m][n][0] + bvv.x;
            float v1 = acc[m][n][1] + bvv.y;
            float v2 = acc[m][n][2] + bvv.z;
            float v3 = acc[m][n][3] + bvv.w;
            if constexpr (ADD) {
                ushort4 rv = *(const ushort4*)(res + oaddr);
                v0 += bf2f(rv.x); v1 += bf2f(rv.y);
                v2 += bf2f(rv.z); v3 += bf2f(rv.w);
            }
            if constexpr (RELU) {
                v0 = fmaxf(v0, 0.f); v1 = fmaxf(v1, 0.f);
                v2 = fmaxf(v2, 0.f); v3 = fmaxf(v3, 0.f);
            }
            ushort4 o;
            o.x = f2bf(v0); o.y = f2bf(v1); o.z = f2bf(v2); o.w = f2bf(v3);
            *(ushort4*)(out + oaddr) = o;
        }
    }
}

// ============ MFMA conv 3x3 stride 2 (128->128), out z NCHW fp32 ===========
__global__ __launch_bounds__(256) void mconv_s2_z(
    const ush* __restrict__ in, const ush* __restrict__ wt,
    const float* __restrict__ bias, float* __restrict__ zout, int Hi, int Wi)
{
    constexpr int CIN = 128, COUT = 128, K = 1152, K32 = 36, XW = 66;
    __shared__ ush sIn[3 * XW * CIN];
    const int Ho = Hi >> 1, Wo = Wi >> 1;
    const int tid = threadIdx.x;
    const int b = blockIdx.z >> 1, co0 = (blockIdx.z & 1) * 64;
    const int yo = blockIdx.y, xo0 = blockIdx.x * 32;

    for (int i = tid; i < 3 * XW * CIN / 8; i += 256) {
        int ci8 = i & 15;
        int r2  = i >> 4;
        int xi  = r2 % XW;
        int row = r2 / XW;
        int gy = 2 * yo + row - 1, gx = 2 * xo0 + xi - 1;
        int4 v = make_int4(0, 0, 0, 0);
        if ((unsigned)gy < (unsigned)Hi && (unsigned)gx < (unsigned)Wi)
            v = *(const int4*)(in + (((size_t)b * Hi + gy) * Wi + gx) * CIN + ci8 * 8);
        int bo = ((row * XW + xi) * CIN + ci8 * 8) * 2;
        *(int4*)((char*)sIn + (bo ^ ((xi & 7) << 4))) = v;
    }
    __syncthreads();

    const int lane = tid & 63, wid = tid >> 6;
    const int wm = wid >> 1, wn = wid & 1;
    const int l15 = lane & 15, lq = lane >> 4;

    f32x4 acc[2] = {};
    const ush* wp  = wt + (size_t)(co0 + wm * 32 + l15) * K + lq * 8;
    const ush* wp2 = wp + 16 * K;
    const int pxl = wn * 16 + l15;

#pragma unroll
    for (int kb = 0; kb < K32; ++kb) {
        const int k0 = kb * 32;
        const int ci0 = k0 % CIN;
        const int kxy = k0 / CIN;
        const int kx = kxy % 3, ky = kxy / 3;
        bf16x8 a0 = *(const bf16x8*)(wp  + k0);
        bf16x8 a1 = *(const bf16x8*)(wp2 + k0);
        const int xl = 2 * pxl + kx;
        const int bo = ((ky * XW + xl) * CIN + ci0 + lq * 8) * 2;
        bf16x8 bfr = *(const bf16x8*)((const char*)sIn + (bo ^ ((xl & 7) << 4)));
        acc[0] = __builtin_amdgcn_mfma_f32_16x16x32_bf16(a0, bfr, acc[0], 0, 0, 0);
        acc[1] = __builtin_amdgcn_mfma_f32_16x16x32_bf16(a1, bfr, acc[1], 0, 0, 0);
    }

    const int px = xo0 + pxl;
#pragma unroll
    for (int m = 0; m < 2; ++m) {
        const int com = co0 + wm * 32 + m * 16 + lq * 4;
        float4 bv = *(const float4*)(bias + com);
#pragma unroll
        for (int r = 0; r < 4; ++r) {
            float v = acc[m][r] + ((const float*)&bv)[r];
            v = fmaxf(v, 0.f);
            zout[(((size_t)b * COUT + com + r) * Ho + yo) * Wo + px] = v;
        }
    }
}

// ============ final conv 64->3, NHWC bf16 in -> NCHW f32 d_out =============
// ROWS=4, wave = one row, 4 px-frags; cout padded to 16.
__global__ __launch_bounds__(256) void mconv_out(
    const ush* __restrict__ in, const ush* __restrict__ wt,
    const float* __restrict__ bias, float* __restrict__ outv, int H, int W)
{
    constexpr int K = 576, K32 = 18, XW = 66, SROWS = 6;
    __shared__ ush sIn[SROWS * XW * 64];
    const int tid = threadIdx.x;
    const int b = blockIdx.z, y0 = blockIdx.y * 4, x0 = blockIdx.x * 64;

    for (int i = tid; i < SROWS * XW * 64 / 8; i += 256) {
        int ci8 = i & 7;
        int r2  = i >> 3;
        int xi  = r2 % XW;
        int row = r2 / XW;
        int gy = y0 + row - 1, gx = x0 + xi - 1;
        int4 v = make_int4(0, 0, 0, 0);
        if ((unsigned)gy < (unsigned)H && (unsigned)gx < (unsigned)W)
            v = *(const int4*)(in + (((size_t)b * H + gy) * W + gx) * 64 + ci8 * 8);
        int bo = ((row * XW + xi) * 64 + ci8 * 8) * 2;
        *(int4*)((char*)sIn + (bo ^ ((xi & 7) << 4))) = v;
    }
    __syncthreads();

    const int lane = tid & 63, wid = tid >> 6;
    const int l15 = lane & 15, lq = lane >> 4;
    const int r = wid;

    f32x4 acc[4] = {};
    const ush* wp = wt + (size_t)l15 * K + lq * 8;

#pragma unroll
    for (int kb = 0; kb < K32; ++kb) {
        const int k0 = kb * 32;
        const int ci0 = k0 % 64;
        const int kxy = k0 / 64;
        const int kx = kxy % 3, ky = kxy / 3;
        bf16x8 a0 = *(const bf16x8*)(wp + k0);
#pragma unroll
        for (int n = 0; n < 4; ++n) {
            const int xi = n * 16 + l15 + kx;
            const int bo = (((r + ky) * XW + xi) * 64 + ci0 + lq * 8) * 2;
            bf16x8 bfr = *(const bf16x8*)((const char*)sIn + (bo ^ ((xi & 7) << 4)));
            acc[n] = __builtin_amdgcn_mfma_f32_16x16x32_bf16(a0, bfr, acc[n], 0, 0, 0);
        }
    }

    const int y = y0 + r;
    if (lq == 0) {
#pragma unroll
        for (int n = 0; n < 4; ++n) {
            const int px = x0 + n * 16 + l15;
#pragma unroll
            for (int ch = 0; ch < 3; ++ch)
                outv[(((size_t)b * 3 + ch) * H + y) * W + px] = acc[n][ch] + bias[ch];
        }
    }
}

// ============== q transpose: NCHW bf16 -> NHWC bf16 (C=H=W=128) ============
__global__ __launch_bounds__(256) void transpose_q(
    const ush* __restrict__ qc, ush* __restrict__ qh)
{
    __shared__ ush sT[128][136];
    const int tid = threadIdx.x;
    const int b = blockIdx.x >> 7, h = blockIdx.x & 127;

    for (int i = tid; i < 2048; i += 256) {
        int c = i >> 4, w8 = i & 15;
        int4 v = *(const int4*)(qc + (((size_t)b * 128 + c) * 128 + h) * 128 + w8 * 8);
        const ush* pv = (const ush*)&v;
#pragma unroll
        for (int j = 0; j < 8; ++j) sT[w8 * 8 + j][c] = pv[j];
    }
    __syncthreads();
    for (int i = tid; i < 2048; i += 256) {
        int w = i >> 4, c8 = i & 15;
        int4 v;
        ush* pv = (ush*)&v;
#pragma unroll
        for (int j = 0; j < 8; ++j) pv[j] = sT[w][c8 * 8 + j];
        *(int4*)(qh + (((size_t)b * 128 + h) * 128 + w) * 128 + c8 * 8) = v;
    }
}

// ================= nearest 2x upsample, NHWC bf16 (C=128) ==================
__global__ void upsample2x_nhwc(const ush* __restrict__ in, ush* __restrict__ out)
{
    long idx = (long)blockIdx.x * 256 + threadIdx.x;
    int c8 = (int)(idx & 15);
    int xx = (int)((idx >> 4) & 255);
    int yy = (int)((idx >> 12) & 255);
    int b  = (int)(idx >> 20);
    int4 v = *(const int4*)(in + (((size_t)b * 128 + (yy >> 1)) * 128 + (xx >> 1)) * 128 + c8 * 8);
    *(int4*)(out + (((size_t)b * 256 + yy) * 256 + xx) * 128 + c8 * 8) = v;
}

// ========================= codebook preparation ============================
__global__ void cb_transpose(const float* __restrict__ cb, float* __restrict__ cbT)
{
    int idx = blockIdx.x * 256 + threadIdx.x;
    if (idx < 1024 * 128) {
        int k = idx >> 7, e = idx & 127;
        cbT[e * 1024 + k] = cb[idx];
    }
}

__global__ void cb_c2(const float* __restrict__ cbT, float* __restrict__ c2)
{
    int k = blockIdx.x * 256 + threadIdx.x;
    if (k < 1024) {
        float s = 0.f;
        for (int e = 0; e < 128; ++e) {
            float v = cbT[e * 1024 + k];
            s = fmaf(v, v, s);
        }
        c2[k] = s;
    }
}

// ============================== quantizer ==================================
__global__ __launch_bounds__(256) void vq_argmin(
    const float* __restrict__ z, const float* __restrict__ cb,
    const float* __restrict__ cbT, const float* __restrict__ c2,
    ush* __restrict__ q, float* __restrict__ partials)
{
    const int row0 = blockIdx.x * 16;
    const int tid  = threadIdx.x;
    const int tr   = tid >> 6;
    const int tk   = tid & 63;

    __shared__ float sZ[16][128];
    __shared__ float sC[32][256];
    __shared__ float sZ2[16];
    __shared__ unsigned long long sKey[16][64];
    __shared__ int   sIdx[16];
    __shared__ float sRed[4];

    for (int idx = tid; idx < 16 * 128; idx += 256)
        sZ[idx >> 7][idx & 127] = z[(size_t)(row0 + (idx >> 7)) * 128 + (idx & 127)];
    __syncthreads();
    if (tid < 16) {
        float s = 0.f;
        for (int e = 0; e < 128; ++e) s = fmaf(sZ[tid][e], sZ[tid][e], s);
        sZ2[tid] = s;
    }
    __syncthreads();

    unsigned long long bk[4] = {~0ull, ~0ull, ~0ull, ~0ull};

    for (int ct = 0; ct < 4; ++ct) {
        float acc[4][4];
#pragma unroll
        for (int i = 0; i < 4; ++i)
#pragma unroll
            for (int j = 0; j < 4; ++j) acc[i][j] = 0.f;

        for (int kt = 0; kt < 4; ++kt) {
            __syncthreads();
            for (int idx = tid; idx < 32 * 256; idx += 256) {
                int e = idx >> 8, c = idx & 255;
                sC[e][c] = cbT[(size_t)(kt * 32 + e) * 1024 + ct * 256 + c];
            }
            __syncthreads();
#pragma unroll 4
            for (int e = 0; e < 32; ++e) {
                float4 cv = *reinterpret_cast<const float4*>(&sC[e][tk << 2]);
                float z0 = sZ[tr * 4 + 0][kt * 32 + e];
                float z1 = sZ[tr * 4 + 1][kt * 32 + e];
                float z2v = sZ[tr * 4 + 2][kt * 32 + e];
                float z3 = sZ[tr * 4 + 3][kt * 32 + e];
                acc[0][0] = fmaf(z0, cv.x, acc[0][0]);
                acc[0][1] = fmaf(z0, cv.y, acc[0][1]);
                acc[0][2] = fmaf(z0, cv.z, acc[0][2]);
                acc[0][3] = fmaf(z0, cv.w, acc[0][3]);
                acc[1][0] = fmaf(z1, cv.x, acc[1][0]);
                acc[1][1] = fmaf(z1, cv.y, acc[1][1]);
                acc[1][2] = fmaf(z1, cv.z, acc[1][2]);
                acc[1][3] = fmaf(z1, cv.w, acc[1][3]);
                acc[2][0] = fmaf(z2v, cv.x, acc[2][0]);
                acc[2][1] = fmaf(z2v, cv.y, acc[2][1]);
                acc[2][2] = fmaf(z2v, cv.z, acc[2][2]);
                acc[2][3] = fmaf(z2v, cv.w, acc[2][3]);
                acc[3][0] = fmaf(z3, cv.x, acc[3][0]);
                acc[3][1] = fmaf(z3, cv.y, acc[3][1]);
                acc[3][2] = fmaf(z3, cv.z, acc[3][2]);
                acc[3][3] = fmaf(z3, cv.w, acc[3][3]);
            }
        }
#pragma unroll
        for (int i = 0; i < 4; ++i) {
            float zz = sZ2[tr * 4 + i];
#pragma unroll
            for (int j = 0; j < 4; ++j) {
                int k = ct * 256 + (tk << 2) + j;
                float d = (zz - 2.0f * acc[i][j]) + c2[k];
                d = fmaxf(d, 0.0f);
                unsigned long long key =
                    ((unsigned long long)__float_as_uint(d) << 32) | (unsigned)k;
                bk[i] = key < bk[i] ? key : bk[i];
            }
        }
    }

#pragma unroll
    for (int i = 0; i < 4; ++i) sKey[tr * 4 + i][tk] = bk[i];
    __syncthreads();
    if (tid < 16) {
        unsigned long long m = sKey[tid][0];
        for (int j = 1; j < 64; ++j) {
            unsigned long long v = sKey[tid][j];
            if (v < m) m = v;
        }
        sIdx[tid] = (int)(m & 0xffffffffull);
    }
    __syncthreads();

    float lsse = 0.f;
    for (int idx = tid; idx < 16 * 128; idx += 256) {
        int r = idx >> 7, e = idx & 127;
        float zv = sZ[r][e];
        float qv = cb[(size_t)sIdx[r] * 128 + e];
        float df = qv - zv;
        lsse = fmaf(df, df, lsse);
        q[(size_t)(row0 + r) * 128 + e] = f2bf(zv + df);   // z + (q - z)
    }
#pragma unroll
    for (int off = 32; off > 0; off >>= 1) lsse += __shfl_down(lsse, off, 64);
    if (tk == 0) sRed[tr] = lsse;
    __syncthreads();
    if (tid == 0) partials[blockIdx.x] = (sRed[0] + sRed[1]) + (sRed[2] + sRed[3]);
}

// ============================ loss finalize ================================
__global__ __launch_bounds__(256) void loss_finish(
    const float* __restrict__ partials, float* __restrict__ outLoss)
{
    __shared__ float sR[256];
    float s = 0.f;
    for (int i = threadIdx.x; i < 8192; i += 256) s += partials[i];
    sR[threadIdx.x] = s;
    __syncthreads();
    for (int st = 128; st > 0; st >>= 1) {
        if (threadIdx.x < st) sR[threadIdx.x] += sR[threadIdx.x + st];
        __syncthreads();
    }
    if (threadIdx.x == 0) {
        float m = sR[0] / 16777216.0f;
        outLoss[0] = m + 0.25f * m;
    }
}

// ============================= launcher ====================================
extern "C" void kernel_launch(void* const* d_in, const int* in_sizes, int n_in,
                              void* d_out, int out_size, void* d_ws, size_t ws_size,
                              hipStream_t stream)
{
    const float* x        = (const float*)d_in[0];
    const float* enc_in_w = (const float*)d_in[1];
    const float* enc_in_b = (const float*)d_in[2];
    const float* rb0_w1   = (const float*)d_in[3];
    const float* rb0_b1   = (const float*)d_in[4];
    const float* rb0_w2   = (const float*)d_in[5];
    const float* rb0_b2   = (const float*)d_in[6];
    const float* rb1_w1   = (const float*)d_in[7];
    const float* rb1_b1   = (const float*)d_in[8];
    const float* rb1_w2   = (const float*)d_in[9];
    const float* rb1_b2   = (const float*)d_in[10];
    const float* rb1_ws   = (const float*)d_in[11];
    const float* rb1_bs   = (const float*)d_in[12];
    const float* down_w   = (const float*)d_in[13];
    const float* down_b   = (const float*)d_in[14];
    const float* codebook = (const float*)d_in[15];
    const float* d1_w1    = (const float*)d_in[16];
    const float* d1_b1    = (const float*)d_in[17];
    const float* d1_w2    = (const float*)d_in[18];
    const float* d1_b2    = (const float*)d_in[19];
    const float* up_w     = (const float*)d_in[20];
    const float* up_b     = (const float*)d_in[21];
    const float* d0_w1    = (const float*)d_in[22];
    const float* d0_b1    = (const float*)d_in[23];
    const float* d0_w2    = (const float*)d_in[24];
    const float* d0_b2    = (const float*)d_in[25];
    const float* out_w    = (const float*)d_in[26];
    const float* out_b    = (const float*)d_in[27];
    (void)in_sizes; (void)n_in; (void)out_size;

    const size_t MB = 1ull << 20;
    char* ws = (char*)d_ws;
    float* partials = (float*)ws;                  // 8192 f32
    float* c2v      = (float*)(ws + 64 * 1024);    // 1024 f32
    float* cbT      = (float*)(ws + 128 * 1024);   // 128x1024 f32
    ush*   wreg     = (ush*)(ws + 1 * MB);         // packed bf16 weights

    ush* w_rb0_1 = wreg + 0;
    ush* w_rb0_2 = wreg + 36864;
    ush* w_rb1_1 = wreg + 73728;
    ush* w_rb1_2 = wreg + 147456;
    ush* w_rb1_s = wreg + 294912;
    ush* w_down  = wreg + 303104;
    ush* w_d1_1  = wreg + 450560;
    ush* w_d1_2  = wreg + 598016;
    ush* w_up    = wreg + 745472;
    ush* w_d0_1  = wreg + 819200;
    ush* w_d0_2  = wreg + 856064;
    ush* w_out   = wreg + 892928;

    char* base = ws + 4 * MB;

    int cbn = 8;
    while (cbn > 1 && 4 * MB + (size_t)cbn * 56 * MB > ws_size) cbn >>= 1;

    auto prep = [&](const float* src, ush* dst, int O, int I, int KSp, int Opad) {
        int tot = Opad * KSp * KSp * I;
        prep_w<<<dim3((tot + 255) / 256), 256, 0, stream>>>(src, dst, O, I, KSp, Opad);
    };
    prep(rb0_w1, w_rb0_1, 64, 64, 3, 64);
    prep(rb0_w2, w_rb0_2, 64, 64, 3, 64);
    prep(rb1_w1, w_rb1_1, 128, 64, 3, 128);
    prep(rb1_w2, w_rb1_2, 128, 128, 3, 128);
    prep(rb1_ws, w_rb1_s, 128, 64, 1, 128);
    prep(down_w, w_down, 128, 128, 3, 128);
    prep(d1_w1, w_d1_1, 128, 128, 3, 128);
    prep(d1_w2, w_d1_2, 128, 128, 3, 128);
    prep(up_w, w_up, 64, 128, 3, 64);
    prep(d0_w1, w_d0_1, 64, 64, 3, 64);
    prep(d0_w2, w_d0_2, 64, 64, 3, 64);
    prep(out_w, w_out, 3, 64, 3, 16);

    cb_transpose<<<dim3(512), 256, 0, stream>>>(codebook, cbT);
    cb_c2<<<dim3(4), 256, 0, stream>>>(cbT, c2v);

    for (int e0 = 0; e0 < 8; e0 += cbn) {
        const float* xc   = x + (size_t)e0 * 3 * 65536;
        float*       outc = (float*)d_out + (size_t)e0 * 3 * 65536;
        float*       pc   = partials + (size_t)e0 * 1024;

        ush*   h0 = (ush*)(base + (size_t)cbn * 0 * MB);
        ush*   t  = (ush*)(base + (size_t)cbn * 8 * MB);
        ush*   r0 = (ush*)(base + (size_t)cbn * 16 * MB);
        ush*   t1 = (ush*)(base + (size_t)cbn * 24 * MB);
        ush*   r1 = (ush*)(base + (size_t)cbn * 40 * MB);
        float* z  = (float*)(base + (size_t)cbn * 0 * MB);
        ush*   qc = (ush*)(base + (size_t)cbn * 8 * MB);
        ush*   qh = (ush*)(base + (size_t)cbn * 12 * MB);
        ush*   dt = (ush*)(base + (size_t)cbn * 16 * MB);
        ush*   dr = (ush*)(base + (size_t)cbn * 20 * MB);
        ush*   up = (ush*)(base + (size_t)cbn * 24 * MB);
        ush*   u  = (ush*)(base + (size_t)cbn * 40 * MB);
        ush*   t2 = (ush*)(base + (size_t)cbn * 0 * MB);
        ush*   r2 = (ush*)(base + (size_t)cbn * 8 * MB);

        // ---------------- encoder ----------------
        enc_in_k<<<dim3(256, cbn), 256, 0, stream>>>(xc, enc_in_w, enc_in_b, h0);
        mconv<64, 64, 3, 4, true, false><<<dim3(4, 64, cbn), 256, 0, stream>>>(
            h0, w_rb0_1, rb0_b1, nullptr, t, 256, 256);
        mconv<64, 64, 3, 4, true, true><<<dim3(4, 64, cbn), 256, 0, stream>>>(
            t, w_rb0_2, rb0_b2, h0, r0, 256, 256);
        mconv<64, 128, 3, 4, true, false><<<dim3(4, 64, 2 * cbn), 256, 0, stream>>>(
            r0, w_rb1_1, rb1_b1, nullptr, t1, 256, 256);
        mconv<64, 128, 1, 4, false, false><<<dim3(4, 64, 2 * cbn), 256, 0, stream>>>(
            r0, w_rb1_s, rb1_bs, nullptr, r1, 256, 256);
        mconv<128, 128, 3, 2, true, true><<<dim3(4, 128, 2 * cbn), 256, 0, stream>>>(
            t1, w_rb1_2, rb1_b2, r1, r1, 256, 256);
        mconv_s2_z<<<dim3(4, 128, 2 * cbn), 256, 0, stream>>>(
            r1, w_down, down_b, z, 256, 256);

        // ---------------- quantizer ----------------
        vq_argmin<<<dim3(cbn * 1024), 256, 0, stream>>>(z, codebook, cbT, c2v, qc, pc);
        transpose_q<<<dim3(cbn * 128), 256, 0, stream>>>(qc, qh);

        // ---------------- decoder ----------------
        mconv<128, 128, 3, 2, true, false><<<dim3(2, 64, 2 * cbn), 256, 0, stream>>>(
            qh, w_d1_1, d1_b1, nullptr, dt, 128, 128);
        mconv<128, 128, 3, 2, true, true><<<dim3(2, 64, 2 * cbn), 256, 0, stream>>>(
            dt, w_d1_2, d1_b2, qh, dr, 128, 128);
        upsample2x_nhwc<<<dim3(cbn * 4096), 256, 0, stream>>>(dr, up);
        mconv<128, 64, 3, 2, true, false><<<dim3(4, 128, cbn), 256, 0, stream>>>(
            up, w_up, up_b, nullptr, u, 256, 256);
        mconv<64, 64, 3, 4, true, false><<<dim3(4, 64, cbn), 256, 0, stream>>>(
            u, w_d0_1, d0_b1, nullptr, t2, 256, 256);
        mconv<64, 64, 3, 4, true, true><<<dim3(4, 64, cbn), 256, 0, stream>>>(
            t2, w_d0_2, d0_b2, u, r2, 256, 256);
        mconv_out<<<dim3(4, 64, cbn), 256, 0, stream>>>(
            r2, w_out, out_b, outc, 256, 256);
    }

    // ---------------- loss ----------------
    loss_finish<<<dim3(1), 256, 0, stream>>>(partials, (float*)d_out + 1572864);
}

// Round 5
// 3075.478 us; speedup vs baseline: 5.8336x; 1.1142x over previous
//
#include <hip/hip_runtime.h>

// ---------------------------------------------------------------------------
// VQ-VAE forward: bf16 MFMA implicit-GEMM convs (NHWC) + split-bf16 MFMA VQ.
// ---------------------------------------------------------------------------

typedef float    f32x4  __attribute__((ext_vector_type(4)));
typedef short    bf16x8 __attribute__((ext_vector_type(8)));
typedef unsigned short ush;
typedef unsigned long long u64;

__device__ __forceinline__ ush f2bf(float f) {
    unsigned u = __float_as_uint(f);
    u += 0x7fff + ((u >> 16) & 1);          // round-to-nearest-even
    return (ush)(u >> 16);
}
__device__ __forceinline__ float bf2f(ush h) {
    return __uint_as_float(((unsigned)h) << 16);
}

// ===================== weight repack OIHW f32 -> K-major bf16 ==============
__global__ void prep_w(const float* __restrict__ src, ush* __restrict__ dst,
                       int O, int I, int KS, int Opad)
{
    int idx = blockIdx.x * 256 + threadIdx.x;
    int K = KS * KS * I;
    if (idx >= Opad * K) return;
    int o = idx / K, k = idx - o * K;
    float v = 0.f;
    if (o < O) {
        int ci = k % I;
        int kxy = k / I;
        int kx = kxy % KS, ky = kxy / KS;
        v = src[((size_t)(o * I + ci) * KS + ky) * KS + kx];
    }
    dst[idx] = f2bf(v);
}

// ============ codebook split hi/lo, pre-swizzled LDS image =================
// 8 chunks of 128 codes; chunk = [hi 32KB | lo 32KB]; element (cidx,e) at
// byte ((cidx*128+e)*2) ^ ((cidx&7)<<4) within each 32KB half.
__global__ void prep_cb_split(const float* __restrict__ cb, char* __restrict__ img)
{
    int idx = blockIdx.x * 256 + threadIdx.x;   // 1024*128
    if (idx >= 1024 * 128) return;
    int k = idx >> 7, e = idx & 127;
    int chunk = k >> 7, cidx = k & 127;
    float c = cb[idx];
    ush hi = f2bf(c);
    ush lo = f2bf(c - bf2f(hi));
    int boff = (((cidx * 128) + e) * 2) ^ ((cidx & 7) << 4);
    char* base = img + (size_t)chunk * 65536;
    *(ush*)(base + boff) = hi;
    *(ush*)(base + boff + 32768) = lo;
}

// ===================== enc_in: 3->64, NCHW f32 in -> NHWC bf16 out =========
__global__ __launch_bounds__(256) void enc_in_k(
    const float* __restrict__ x, const float* __restrict__ w,
    const float* __restrict__ bias, ush* __restrict__ out)
{
    __shared__ float sX[3][3][260];
    __shared__ float sW[27][64];
    __shared__ float sB[64];
    const int tid = threadIdx.x;
    const int y = blockIdx.x, b = blockIdx.y;

    for (int i = tid; i < 3 * 3 * 258; i += 256) {
        int xi = i % 258;
        int r  = (i / 258) % 3;
        int c  = i / 774;
        int gy = y + r - 1, gx = xi - 1;
        float v = 0.f;
        if ((unsigned)gy < 256u && (unsigned)gx < 256u)
            v = x[(((size_t)b * 3 + c) * 256 + gy) * 256 + gx];
        sX[c][r][xi] = v;
    }
    for (int i = tid; i < 1728; i += 256) {
        int co = i & 63, k = i >> 6;
        int c = k % 3, kxy = k / 3;
        int kx = kxy % 3, ky = kxy / 3;
        sW[k][co] = w[co * 27 + c * 9 + ky * 3 + kx];
    }
    if (tid < 64) sB[tid] = bias[tid];
    __syncthreads();

    float acc[64];
#pragma unroll
    for (int c = 0; c < 64; ++c) acc[c] = 0.f;
    const int px = tid;
#pragma unroll
    for (int k = 0; k < 27; ++k) {
        const int c = k % 3, kxy = k / 3;
        const int kx = kxy % 3, ky = kxy / 3;
        float iv = sX[c][ky][px + kx];
#pragma unroll
        for (int co = 0; co < 64; ++co) acc[co] = fmaf(iv, sW[k][co], acc[co]);
    }
    ush* op = out + (((size_t)b * 256 + y) * 256 + px) * 64;
#pragma unroll
    for (int c8 = 0; c8 < 8; ++c8) {
        ush tmp[8];
#pragma unroll
        for (int j = 0; j < 8; ++j) tmp[j] = f2bf(acc[c8 * 8 + j] + sB[c8 * 8 + j]);
        *(int4*)(op + c8 * 8) = *(const int4*)tmp;
    }
}

// ===================== MFMA conv, stride 1, NHWC bf16 ======================
template<int CIN, int COUT, int KS, int ROWS, bool RELU, bool ADD>
__global__ __launch_bounds__(256) void mconv(
    const ush* __restrict__ in, const ush* __restrict__ wt,
    const float* __restrict__ bias, const ush* __restrict__ res,
    ush* __restrict__ out, int H, int W)
{
    constexpr int HALO  = KS / 2;
    constexpr int XW    = 64 + 2 * HALO;
    constexpr int K     = KS * KS * CIN;
    constexpr int K32   = K / 32;
    constexpr int COB   = COUT / 64;
    constexpr int SROWS = ROWS + 2 * HALO;
    constexpr int F     = ROWS;
    constexpr int WPR   = 4 / ROWS;

    __shared__ ush sIn[SROWS * XW * CIN];

    const int tid = threadIdx.x;
    const int b   = blockIdx.z / COB;
    const int co0 = (blockIdx.z % COB) * 64;
    const int y0  = blockIdx.y * ROWS;
    const int x0  = blockIdx.x * 64;

    constexpr int CHUNKS = SROWS * XW * CIN / 8;
    for (int i = tid; i < CHUNKS; i += 256) {
        int ci8 = i % (CIN / 8);
        int r2  = i / (CIN / 8);
        int xi  = r2 % XW;
        int row = r2 / XW;
        int gy = y0 + row - HALO;
        int gx = x0 + xi - HALO;
        int4 v = make_int4(0, 0, 0, 0);
        if ((unsigned)gy < (unsigned)H && (unsigned)gx < (unsigned)W)
            v = *(const int4*)(in + (((size_t)b * H + gy) * W + gx) * CIN + ci8 * 8);
        int bo = ((row * XW + xi) * CIN + ci8 * 8) * 2;
        *(int4*)((char*)sIn + (bo ^ ((xi & 7) << 4))) = v;
    }
    __syncthreads();

    const int lane = tid & 63, wid = tid >> 6;
    const int r   = wid / WPR;
    const int fb  = (wid % WPR) * F;
    const int l15 = lane & 15, lq = lane >> 4;

    f32x4 acc[4][F] = {};
    const ush* wp = wt + (size_t)(co0 + l15) * K + lq * 8;

#pragma unroll
    for (int kb = 0; kb < K32; ++kb) {
        const int k0  = kb * 32;
        const int ci0 = k0 % CIN;
        const int kxy = k0 / CIN;
        const int kx = kxy % KS, ky = kxy / KS;
        bf16x8 a[4];
#pragma unroll
        for (int m = 0; m < 4; ++m)
            a[m] = *(const bf16x8*)(wp + (size_t)m * 16 * K + k0);
#pragma unroll
        for (int n = 0; n < F; ++n) {
            const int xi = (fb + n) * 16 + l15 + kx;
            const int bo = (((r + ky) * XW + xi) * CIN + ci0 + lq * 8) * 2;
            bf16x8 bv = *(const bf16x8*)((const char*)sIn + (bo ^ ((xi & 7) << 4)));
#pragma unroll
            for (int m = 0; m < 4; ++m)
                acc[m][n] = __builtin_amdgcn_mfma_f32_16x16x32_bf16(a[m], bv, acc[m][n], 0, 0, 0);
        }
    }

    const int y = y0 + r;
#pragma unroll
    for (int m = 0; m < 4; ++m) {
        const int com = co0 + m * 16 + lq * 4;
        float4 bvv = *(const float4*)(bias + com);
#pragma unroll
        for (int n = 0; n < F; ++n) {
            const int px = x0 + (fb + n) * 16 + l15;
            size_t oaddr = (((size_t)b * H + y) * W + px) * COUT + com;
            float v0 = acc[m][n][0] + bvv.x;
            float v1 = acc[m][n][1] + bvv.y;
            float v2 = acc[m][n][2] + bvv.z;
            float v3 = acc[m][n][3] + bvv.w;
            if constexpr (ADD) {
                ushort4 rv = *(const ushort4*)(res + oaddr);
                v0 += bf2f(rv.x); v1 += bf2f(rv.y);
                v2 += bf2f(rv.z); v3 += bf2f(rv.w);
            }
            if constexpr (RELU) {
                v0 = fmaxf(v0, 0.f); v1 = fmaxf(v1, 0.f);
                v2 = fmaxf(v2, 0.f); v3 = fmaxf(v3, 0.f);
            }
            ushort4 o;
            o.x = f2bf(v0); o.y = f2bf(v1); o.z = f2bf(v2); o.w = f2bf(v3);
            *(ushort4*)(out + oaddr) = o;
        }
    }
}

// ============ MFMA conv 3x3 stride 2 (128->128), out z NCHW fp32 ===========
__global__ __launch_bounds__(256) void mconv_s2_z(
    const ush* __restrict__ in, const ush* __restrict__ wt,
    const float* __restrict__ bias, float* __restrict__ zout, int Hi, int Wi)
{
    constexpr int CIN = 128, COUT = 128, K = 1152, K32 = 36, XW = 66;
    __shared__ ush sIn[3 * XW * CIN];
    const int Ho = Hi >> 1, Wo = Wi >> 1;
    const int tid = threadIdx.x;
    const int b = blockIdx.z >> 1, co0 = (blockIdx.z & 1) * 64;
    const int yo = blockIdx.y, xo0 = blockIdx.x * 32;

    for (int i = tid; i < 3 * XW * CIN / 8; i += 256) {
        int ci8 = i & 15;
        int r2  = i >> 4;
        int xi  = r2 % XW;
        int row = r2 / XW;
        int gy = 2 * yo + row - 1, gx = 2 * xo0 + xi - 1;
        int4 v = make_int4(0, 0, 0, 0);
        if ((unsigned)gy < (unsigned)Hi && (unsigned)gx < (unsigned)Wi)
            v = *(const int4*)(in + (((size_t)b * Hi + gy) * Wi + gx) * CIN + ci8 * 8);
        int bo = ((row * XW + xi) * CIN + ci8 * 8) * 2;
        *(int4*)((char*)sIn + (bo ^ ((xi & 7) << 4))) = v;
    }
    __syncthreads();

    const int lane = tid & 63, wid = tid >> 6;
    const int wm = wid >> 1, wn = wid & 1;
    const int l15 = lane & 15, lq = lane >> 4;

    f32x4 acc[2] = {};
    const ush* wp  = wt + (size_t)(co0 + wm * 32 + l15) * K + lq * 8;
    const ush* wp2 = wp + 16 * K;
    const int pxl = wn * 16 + l15;

#pragma unroll
    for (int kb = 0; kb < K32; ++kb) {
        const int k0 = kb * 32;
        const int ci0 = k0 % CIN;
        const int kxy = k0 / CIN;
        const int kx = kxy % 3, ky = kxy / 3;
        bf16x8 a0 = *(const bf16x8*)(wp  + k0);
        bf16x8 a1 = *(const bf16x8*)(wp2 + k0);
        const int xl = 2 * pxl + kx;
        const int bo = ((ky * XW + xl) * CIN + ci0 + lq * 8) * 2;
        bf16x8 bfr = *(const bf16x8*)((const char*)sIn + (bo ^ ((xl & 7) << 4)));
        acc[0] = __builtin_amdgcn_mfma_f32_16x16x32_bf16(a0, bfr, acc[0], 0, 0, 0);
        acc[1] = __builtin_amdgcn_mfma_f32_16x16x32_bf16(a1, bfr, acc[1], 0, 0, 0);
    }

    const int px = xo0 + pxl;
#pragma unroll
    for (int m = 0; m < 2; ++m) {
        const int com = co0 + wm * 32 + m * 16 + lq * 4;
        float4 bv = *(const float4*)(bias + com);
#pragma unroll
        for (int r = 0; r < 4; ++r) {
            float v = acc[m][r] + ((const float*)&bv)[r];
            v = fmaxf(v, 0.f);
            zout[(((size_t)b * COUT + com + r) * Ho + yo) * Wo + px] = v;
        }
    }
}

// ============ final conv 64->3, NHWC bf16 in -> NCHW f32 d_out =============
__global__ __launch_bounds__(256) void mconv_out(
    const ush* __restrict__ in, const ush* __restrict__ wt,
    const float* __restrict__ bias, float* __restrict__ outv, int H, int W)
{
    constexpr int K = 576, K32 = 18, XW = 66, SROWS = 6;
    __shared__ ush sIn[SROWS * XW * 64];
    const int tid = threadIdx.x;
    const int b = blockIdx.z, y0 = blockIdx.y * 4, x0 = blockIdx.x * 64;

    for (int i = tid; i < SROWS * XW * 64 / 8; i += 256) {
        int ci8 = i & 7;
        int r2  = i >> 3;
        int xi  = r2 % XW;
        int row = r2 / XW;
        int gy = y0 + row - 1, gx = x0 + xi - 1;
        int4 v = make_int4(0, 0, 0, 0);
        if ((unsigned)gy < (unsigned)H && (unsigned)gx < (unsigned)W)
            v = *(const int4*)(in + (((size_t)b * H + gy) * W + gx) * 64 + ci8 * 8);
        int bo = ((row * XW + xi) * 64 + ci8 * 8) * 2;
        *(int4*)((char*)sIn + (bo ^ ((xi & 7) << 4))) = v;
    }
    __syncthreads();

    const int lane = tid & 63, wid = tid >> 6;
    const int l15 = lane & 15, lq = lane >> 4;
    const int r = wid;

    f32x4 acc[4] = {};
    const ush* wp = wt + (size_t)l15 * K + lq * 8;

#pragma unroll
    for (int kb = 0; kb < K32; ++kb) {
        const int k0 = kb * 32;
        const int ci0 = k0 % 64;
        const int kxy = k0 / 64;
        const int kx = kxy % 3, ky = kxy / 3;
        bf16x8 a0 = *(const bf16x8*)(wp + k0);
#pragma unroll
        for (int n = 0; n < 4; ++n) {
            const int xi = n * 16 + l15 + kx;
            const int bo = (((r + ky) * XW + xi) * 64 + ci0 + lq * 8) * 2;
            bf16x8 bfr = *(const bf16x8*)((const char*)sIn + (bo ^ ((xi & 7) << 4)));
            acc[n] = __builtin_amdgcn_mfma_f32_16x16x32_bf16(a0, bfr, acc[n], 0, 0, 0);
        }
    }

    const int y = y0 + r;
    if (lq == 0) {
#pragma unroll
        for (int n = 0; n < 4; ++n) {
            const int px = x0 + n * 16 + l15;
#pragma unroll
            for (int ch = 0; ch < 3; ++ch)
                outv[(((size_t)b * 3 + ch) * H + y) * W + px] = acc[n][ch] + bias[ch];
        }
    }
}

// ============== q transpose: NCHW bf16 -> NHWC bf16 (C=H=W=128) ============
__global__ __launch_bounds__(256) void transpose_q(
    const ush* __restrict__ qc, ush* __restrict__ qh)
{
    __shared__ ush sT[128][136];
    const int tid = threadIdx.x;
    const int b = blockIdx.x >> 7, h = blockIdx.x & 127;

    for (int i = tid; i < 2048; i += 256) {
        int c = i >> 4, w8 = i & 15;
        int4 v = *(const int4*)(qc + (((size_t)b * 128 + c) * 128 + h) * 128 + w8 * 8);
        const ush* pv = (const ush*)&v;
#pragma unroll
        for (int j = 0; j < 8; ++j) sT[w8 * 8 + j][c] = pv[j];
    }
    __syncthreads();
    for (int i = tid; i < 2048; i += 256) {
        int w = i >> 4, c8 = i & 15;
        int4 v;
        ush* pv = (ush*)&v;
#pragma unroll
        for (int j = 0; j < 8; ++j) pv[j] = sT[w][c8 * 8 + j];
        *(int4*)(qh + (((size_t)b * 128 + h) * 128 + w) * 128 + c8 * 8) = v;
    }
}

// ================= nearest 2x upsample, NHWC bf16 (C=128) ==================
__global__ void upsample2x_nhwc(const ush* __restrict__ in, ush* __restrict__ out)
{
    long idx = (long)blockIdx.x * 256 + threadIdx.x;
    int c8 = (int)(idx & 15);
    int xx = (int)((idx >> 4) & 255);
    int yy = (int)((idx >> 12) & 255);
    int b  = (int)(idx >> 20);
    int4 v = *(const int4*)(in + (((size_t)b * 128 + (yy >> 1)) * 128 + (xx >> 1)) * 128 + c8 * 8);
    *(int4*)(out + (((size_t)b * 256 + yy) * 256 + xx) * 128 + c8 * 8) = v;
}

// ========================= codebook c^2 ====================================
__global__ void cb_transpose(const float* __restrict__ cb, float* __restrict__ cbT)
{
    int idx = blockIdx.x * 256 + threadIdx.x;
    if (idx < 1024 * 128) {
        int k = idx >> 7, e = idx & 127;
        cbT[e * 1024 + k] = cb[idx];
    }
}

__global__ void cb_c2(const float* __restrict__ cbT, float* __restrict__ c2)
{
    int k = blockIdx.x * 256 + threadIdx.x;
    if (k < 1024) {
        float s = 0.f;
        for (int e = 0; e < 128; ++e) {
            float v = cbT[e * 1024 + k];
            s = fmaf(v, v, s);
        }
        c2[k] = s;
    }
}

// ===================== MFMA quantizer ======================================
// Block: 128 rows x 1024 codes; 4 waves x 32 rows. Split-bf16 3-pass dot
// (zhi*chi + zlo*chi + zhi*clo), d = (z2 - 2*dot) + c2, fmax-clamp, u64 key.
__global__ __launch_bounds__(256) void vq_mfma(
    const float* __restrict__ z, const float* __restrict__ cb,
    const char* __restrict__ cbImg, const float* __restrict__ c2,
    ush* __restrict__ q, float* __restrict__ partials)
{
    __shared__ ush   sB[32768];        // 64 KB codebook chunk (hi|lo)
    __shared__ float sC2[1024];
    __shared__ float sZ2p[128][2];
    __shared__ float sZ2[128];
    __shared__ int   sIdx[128];
    __shared__ float sRed[4];

    const int tid = threadIdx.x;
    const int wid = tid >> 6, lane = tid & 63;
    const int l15 = lane & 15, lq = lane >> 4;
    const size_t row0 = (size_t)blockIdx.x * 128;

    // ---- stage c2 ----
    for (int i = tid; i < 1024; i += 256) sC2[i] = c2[i];

    // ---- z2 per row (half-row per thread, sequential fp32) ----
    {
        int row = tid >> 1, half = tid & 1;
        const float* zp = z + (row0 + row) * 128 + half * 64;
        float s = 0.f;
        for (int j = 0; j < 16; ++j) {
            float4 v = *(const float4*)(zp + j * 4);
            s = fmaf(v.x, v.x, s); s = fmaf(v.y, v.y, s);
            s = fmaf(v.z, v.z, s); s = fmaf(v.w, v.w, s);
        }
        sZ2p[row][half] = s;
    }
    __syncthreads();
    if (tid < 128) sZ2[tid] = sZ2p[tid][0] + sZ2p[tid][1];

    // ---- preload A fragments (z rows, split hi/lo) ----
    bf16x8 ahi[2][4], alo[2][4];
#pragma unroll
    for (int rt = 0; rt < 2; ++rt) {
#pragma unroll
        for (int ks = 0; ks < 4; ++ks) {
            const float* zp = z + (row0 + wid * 32 + rt * 16 + l15) * 128 + ks * 32 + lq * 8;
            float4 v0 = *(const float4*)zp;
            float4 v1 = *(const float4*)(zp + 4);
            float f[8] = {v0.x, v0.y, v0.z, v0.w, v1.x, v1.y, v1.z, v1.w};
            bf16x8 h, l;
#pragma unroll
            for (int j = 0; j < 8; ++j) {
                ush hb = f2bf(f[j]);
                h[j] = (short)hb;
                l[j] = (short)f2bf(f[j] - bf2f(hb));
            }
            ahi[rt][ks] = h; alo[rt][ks] = l;
        }
    }

    u64 bk[2][4];
#pragma unroll
    for (int rt = 0; rt < 2; ++rt)
#pragma unroll
        for (int rg = 0; rg < 4; ++rg) bk[rt][rg] = ~0ull;

#pragma unroll 1
    for (int p = 0; p < 8; ++p) {
        __syncthreads();
        // stage 64 KB chunk (pre-swizzled image -> linear LDS)
        {
            const int4* gsrc = (const int4*)(cbImg + (size_t)p * 65536);
            int4* ldst = (int4*)sB;
#pragma unroll
            for (int it = 0; it < 16; ++it)
                ldst[it * 256 + tid] = gsrc[it * 256 + tid];
        }
        __syncthreads();

        f32x4 acc[2][8] = {};
#pragma unroll
        for (int ks = 0; ks < 4; ++ks) {
#pragma unroll
            for (int ct = 0; ct < 8; ++ct) {
                int cidx = ct * 16 + l15;
                int boff = ((cidx * 128 + ks * 32 + lq * 8) * 2) ^ ((cidx & 7) << 4);
                bf16x8 bh = *(const bf16x8*)((const char*)sB + boff);
                bf16x8 bl = *(const bf16x8*)((const char*)sB + boff + 32768);
#pragma unroll
                for (int rt = 0; rt < 2; ++rt) {
                    acc[rt][ct] = __builtin_amdgcn_mfma_f32_16x16x32_bf16(ahi[rt][ks], bh, acc[rt][ct], 0, 0, 0);
                    acc[rt][ct] = __builtin_amdgcn_mfma_f32_16x16x32_bf16(alo[rt][ks], bh, acc[rt][ct], 0, 0, 0);
                    acc[rt][ct] = __builtin_amdgcn_mfma_f32_16x16x32_bf16(ahi[rt][ks], bl, acc[rt][ct], 0, 0, 0);
                }
            }
        }
        // fold distances into running min keys
#pragma unroll
        for (int rt = 0; rt < 2; ++rt) {
#pragma unroll
            for (int ct = 0; ct < 8; ++ct) {
                int code = p * 128 + ct * 16 + l15;
                float cc = sC2[code];
#pragma unroll
                for (int rg = 0; rg < 4; ++rg) {
                    float z2 = sZ2[wid * 32 + rt * 16 + lq * 4 + rg];
                    float d = (z2 - 2.0f * acc[rt][ct][rg]) + cc;
                    d = fmaxf(d, 0.f);
                    u64 key = ((u64)__float_as_uint(d) << 32) | (unsigned)code;
                    if (key < bk[rt][rg]) bk[rt][rg] = key;
                }
            }
        }
    }

    // ---- reduce across the 16 lanes of each lq-group ----
#pragma unroll
    for (int rt = 0; rt < 2; ++rt) {
#pragma unroll
        for (int rg = 0; rg < 4; ++rg) {
            u64 k = bk[rt][rg];
#pragma unroll
            for (int m = 1; m < 16; m <<= 1) {
                u64 o = __shfl_xor(k, m, 64);
                if (o < k) k = o;
            }
            if (l15 == 0)
                sIdx[wid * 32 + rt * 16 + lq * 4 + rg] = (int)(k & 0xffffffffull);
        }
    }
    __syncthreads();

    // ---- q write + sse ----
    float lsse = 0.f;
    {
        int row = tid >> 1, half = tid & 1;
        int code = sIdx[row];
        const float* cbrow = cb + (size_t)code * 128 + half * 64;
        const float* zrow  = z + (row0 + row) * 128 + half * 64;
        ush* qrow = q + (row0 + row) * 128 + half * 64;
        for (int j = 0; j < 16; ++j) {
            float4 cv = *(const float4*)(cbrow + j * 4);
            float4 zv = *(const float4*)(zrow + j * 4);
            float d0 = cv.x - zv.x, d1 = cv.y - zv.y;
            float d2 = cv.z - zv.z, d3 = cv.w - zv.w;
            lsse = fmaf(d0, d0, lsse); lsse = fmaf(d1, d1, lsse);
            lsse = fmaf(d2, d2, lsse); lsse = fmaf(d3, d3, lsse);
            ushort4 o;
            o.x = f2bf(zv.x + d0); o.y = f2bf(zv.y + d1);
            o.z = f2bf(zv.z + d2); o.w = f2bf(zv.w + d3);
            *(ushort4*)(qrow + j * 4) = o;
        }
    }
#pragma unroll
    for (int off = 32; off > 0; off >>= 1) lsse += __shfl_down(lsse, off, 64);
    if (lane == 0) sRed[wid] = lsse;
    __syncthreads();
    if (tid == 0) partials[blockIdx.x] = (sRed[0] + sRed[1]) + (sRed[2] + sRed[3]);
}

// ============================ loss finalize ================================
__global__ __launch_bounds__(256) void loss_finish(
    const float* __restrict__ partials, float* __restrict__ outLoss)
{
    __shared__ float sR[256];
    float s = 0.f;
    for (int i = threadIdx.x; i < 1024; i += 256) s += partials[i];
    sR[threadIdx.x] = s;
    __syncthreads();
    for (int st = 128; st > 0; st >>= 1) {
        if (threadIdx.x < st) sR[threadIdx.x] += sR[threadIdx.x + st];
        __syncthreads();
    }
    if (threadIdx.x == 0) {
        float m = sR[0] / 16777216.0f;
        outLoss[0] = m + 0.25f * m;
    }
}

// ============================= launcher ====================================
extern "C" void kernel_launch(void* const* d_in, const int* in_sizes, int n_in,
                              void* d_out, int out_size, void* d_ws, size_t ws_size,
                              hipStream_t stream)
{
    const float* x        = (const float*)d_in[0];
    const float* enc_in_w = (const float*)d_in[1];
    const float* enc_in_b = (const float*)d_in[2];
    const float* rb0_w1   = (const float*)d_in[3];
    const float* rb0_b1   = (const float*)d_in[4];
    const float* rb0_w2   = (const float*)d_in[5];
    const float* rb0_b2   = (const float*)d_in[6];
    const float* rb1_w1   = (const float*)d_in[7];
    const float* rb1_b1   = (const float*)d_in[8];
    const float* rb1_w2   = (const float*)d_in[9];
    const float* rb1_b2   = (const float*)d_in[10];
    const float* rb1_ws   = (const float*)d_in[11];
    const float* rb1_bs   = (const float*)d_in[12];
    const float* down_w   = (const float*)d_in[13];
    const float* down_b   = (const float*)d_in[14];
    const float* codebook = (const float*)d_in[15];
    const float* d1_w1    = (const float*)d_in[16];
    const float* d1_b1    = (const float*)d_in[17];
    const float* d1_w2    = (const float*)d_in[18];
    const float* d1_b2    = (const float*)d_in[19];
    const float* up_w     = (const float*)d_in[20];
    const float* up_b     = (const float*)d_in[21];
    const float* d0_w1    = (const float*)d_in[22];
    const float* d0_b1    = (const float*)d_in[23];
    const float* d0_w2    = (const float*)d_in[24];
    const float* d0_b2    = (const float*)d_in[25];
    const float* out_w    = (const float*)d_in[26];
    const float* out_b    = (const float*)d_in[27];
    (void)in_sizes; (void)n_in; (void)out_size;

    const size_t MB = 1ull << 20;
    char* ws = (char*)d_ws;
    float* partials = (float*)ws;                  // 1024 f32
    float* c2v      = (float*)(ws + 32 * 1024);    // 1024 f32
    float* cbT      = (float*)(ws + 64 * 1024);    // 128x1024 f32 (512 KB)
    char*  cbImg    = ws + 1 * MB;                 // 512 KB split hi/lo image
    ush*   wreg     = (ush*)(ws + 1 * MB + 512 * 1024);

    ush* w_rb0_1 = wreg + 0;
    ush* w_rb0_2 = wreg + 36864;
    ush* w_rb1_1 = wreg + 73728;
    ush* w_rb1_2 = wreg + 147456;
    ush* w_rb1_s = wreg + 294912;
    ush* w_down  = wreg + 303104;
    ush* w_d1_1  = wreg + 450560;
    ush* w_d1_2  = wreg + 598016;
    ush* w_up    = wreg + 745472;
    ush* w_d0_1  = wreg + 819200;
    ush* w_d0_2  = wreg + 856064;
    ush* w_out   = wreg + 892928;

    char* base = ws + 4 * MB;

    int cbn = 8;
    while (cbn > 1 && 4 * MB + (size_t)cbn * 56 * MB > ws_size) cbn >>= 1;

    auto prep = [&](const float* src, ush* dst, int O, int I, int KSp, int Opad) {
        int tot = Opad * KSp * KSp * I;
        prep_w<<<dim3((tot + 255) / 256), 256, 0, stream>>>(src, dst, O, I, KSp, Opad);
    };
    prep(rb0_w1, w_rb0_1, 64, 64, 3, 64);
    prep(rb0_w2, w_rb0_2, 64, 64, 3, 64);
    prep(rb1_w1, w_rb1_1, 128, 64, 3, 128);
    prep(rb1_w2, w_rb1_2, 128, 128, 3, 128);
    prep(rb1_ws, w_rb1_s, 128, 64, 1, 128);
    prep(down_w, w_down, 128, 128, 3, 128);
    prep(d1_w1, w_d1_1, 128, 128, 3, 128);
    prep(d1_w2, w_d1_2, 128, 128, 3, 128);
    prep(up_w, w_up, 64, 128, 3, 64);
    prep(d0_w1, w_d0_1, 64, 64, 3, 64);
    prep(d0_w2, w_d0_2, 64, 64, 3, 64);
    prep(out_w, w_out, 3, 64, 3, 16);

    cb_transpose<<<dim3(512), 256, 0, stream>>>(codebook, cbT);
    cb_c2<<<dim3(4), 256, 0, stream>>>(cbT, c2v);
    prep_cb_split<<<dim3(512), 256, 0, stream>>>(codebook, cbImg);

    for (int e0 = 0; e0 < 8; e0 += cbn) {
        const float* xc   = x + (size_t)e0 * 3 * 65536;
        float*       outc = (float*)d_out + (size_t)e0 * 3 * 65536;

        ush*   h0 = (ush*)(base + (size_t)cbn * 0 * MB);
        ush*   t  = (ush*)(base + (size_t)cbn * 8 * MB);
        ush*   r0 = (ush*)(base + (size_t)cbn * 16 * MB);
        ush*   t1 = (ush*)(base + (size_t)cbn * 24 * MB);
        ush*   r1 = (ush*)(base + (size_t)cbn * 40 * MB);
        float* z  = (float*)(base + (size_t)cbn * 0 * MB);
        ush*   qc = (ush*)(base + (size_t)cbn * 8 * MB);
        ush*   qh = (ush*)(base + (size_t)cbn * 12 * MB);
        ush*   dt = (ush*)(base + (size_t)cbn * 16 * MB);
        ush*   dr = (ush*)(base + (size_t)cbn * 20 * MB);
        ush*   up = (ush*)(base + (size_t)cbn * 24 * MB);
        ush*   u  = (ush*)(base + (size_t)cbn * 40 * MB);
        ush*   t2 = (ush*)(base + (size_t)cbn * 0 * MB);
        ush*   r2 = (ush*)(base + (size_t)cbn * 8 * MB);

        // ---------------- encoder ----------------
        enc_in_k<<<dim3(256, cbn), 256, 0, stream>>>(xc, enc_in_w, enc_in_b, h0);
        mconv<64, 64, 3, 4, true, false><<<dim3(4, 64, cbn), 256, 0, stream>>>(
            h0, w_rb0_1, rb0_b1, nullptr, t, 256, 256);
        mconv<64, 64, 3, 4, true, true><<<dim3(4, 64, cbn), 256, 0, stream>>>(
            t, w_rb0_2, rb0_b2, h0, r0, 256, 256);
        mconv<64, 128, 3, 4, true, false><<<dim3(4, 64, 2 * cbn), 256, 0, stream>>>(
            r0, w_rb1_1, rb1_b1, nullptr, t1, 256, 256);
        mconv<64, 128, 1, 4, false, false><<<dim3(4, 64, 2 * cbn), 256, 0, stream>>>(
            r0, w_rb1_s, rb1_bs, nullptr, r1, 256, 256);
        mconv<128, 128, 3, 2, true, true><<<dim3(4, 128, 2 * cbn), 256, 0, stream>>>(
            t1, w_rb1_2, rb1_b2, r1, r1, 256, 256);
        mconv_s2_z<<<dim3(4, 128, 2 * cbn), 256, 0, stream>>>(
            r1, w_down, down_b, z, 256, 256);

        // ---------------- quantizer ----------------
        vq_mfma<<<dim3(cbn * 128), 256, 0, stream>>>(
            z, codebook, cbImg, c2v, qc, partials + (size_t)e0 * 128);
        transpose_q<<<dim3(cbn * 128), 256, 0, stream>>>(qc, qh);

        // ---------------- decoder ----------------
        mconv<128, 128, 3, 2, true, false><<<dim3(2, 64, 2 * cbn), 256, 0, stream>>>(
            qh, w_d1_1, d1_b1, nullptr, dt, 128, 128);
        mconv<128, 128, 3, 2, true, true><<<dim3(2, 64, 2 * cbn), 256, 0, stream>>>(
            dt, w_d1_2, d1_b2, qh, dr, 128, 128);
        upsample2x_nhwc<<<dim3(cbn * 4096), 256, 0, stream>>>(dr, up);
        mconv<128, 64, 3, 2, true, false><<<dim3(4, 128, cbn), 256, 0, stream>>>(
            up, w_up, up_b, nullptr, u, 256, 256);
        mconv<64, 64, 3, 4, true, false><<<dim3(4, 64, cbn), 256, 0, stream>>>(
            u, w_d0_1, d0_b1, nullptr, t2, 256, 256);
        mconv<64, 64, 3, 4, true, true><<<dim3(4, 64, cbn), 256, 0, stream>>>(
            t2, w_d0_2, d0_b2, u, r2, 256, 256);
        mconv_out<<<dim3(4, 64, cbn), 256, 0, stream>>>(
            r2, w_out, out_b, outc, 256, 256);
    }

    // ---------------- loss ----------------
    loss_finish<<<dim3(1), 256, 0, stream>>>(partials, (float*)d_out + 1572864);
}